// Round 1
// baseline (462.957 us; speedup 1.0000x reference)
//
#include <hip/hip_runtime.h>
#include <hip/hip_bf16.h>
#include <stdint.h>

typedef __bf16 bf16x8 __attribute__((ext_vector_type(8)));
typedef float f32x4 __attribute__((ext_vector_type(4)));

#define B_DIM 16
#define TD 1024
#define TE 1024
#define DD 1024

typedef __attribute__((address_space(1))) void as1_void;
typedef __attribute__((address_space(3))) void as3_void;

// global -> LDS direct copy, 16B per lane. LDS dest must be linear in lane order.
#define GLL16(gp, lp) \
  __builtin_amdgcn_global_load_lds((as1_void*)(gp), (as3_void*)(lp), 16, 0, 0)

__device__ __forceinline__ uint32_t rne_bf16(float x) {
  uint32_t u = __builtin_bit_cast(uint32_t, x);
  return (u + 0x7FFFu + ((u >> 16) & 1u)) >> 16;
}

// RNE two-term split: x ~= hi + lo, both bf16. Exact Veltkamp-style residual.
__device__ __forceinline__ void split2(float x, uint32_t& hi, uint32_t& lo) {
  uint32_t h = rne_bf16(x);
  float hf = __builtin_bit_cast(float, h << 16);
  hi = h;
  lo = rne_bf16(x - hf);
}

// ---------------------------------------------------------------------------
// P0a: dec fp32 -> dec_hi, dec_lo bf16 (each element split exactly once).
// ---------------------------------------------------------------------------
__global__ __launch_bounds__(256)
void p0a_split_dec(const float4* __restrict__ dec4, uint32_t* __restrict__ dhi,
                   uint32_t* __restrict__ dlo) {
  size_t g = (size_t)blockIdx.x * 256 + threadIdx.x;
#pragma unroll
  for (int s = 0; s < 8; ++s, g += 524288) {
    float4 v = dec4[g];
    uint32_t h0, l0, h1, l1, h2, l2, h3, l3;
    split2(v.x, h0, l0);
    split2(v.y, h1, l1);
    split2(v.z, h2, l2);
    split2(v.w, h3, l3);
    *(uint2*)&dhi[g * 2] = make_uint2(h0 | (h1 << 16), h2 | (h3 << 16));
    *(uint2*)&dlo[g * 2] = make_uint2(l0 | (l1 << 16), l2 | (l3 << 16));
  }
}

// ---------------------------------------------------------------------------
// P0b: enc fp32 -> enc_hi, enc_lo bf16 [b][e][d], plus encT bf16 [b][d][e]
// (transposed hi copy for K3's B operand) via a 64x64 LDS tile.
// ---------------------------------------------------------------------------
__global__ __launch_bounds__(256)
void p0b_split_enc(const float* __restrict__ enc, uint32_t* __restrict__ ehi,
                   uint32_t* __restrict__ elo, uint16_t* __restrict__ eT) {
  __shared__ uint16_t TT[64][65];
  const int tid = threadIdx.x;
  const int b = blockIdx.z;
  const int d0 = (blockIdx.x & 15) * 64, e0 = (blockIdx.x >> 4) * 64;
  const float* src = enc + (size_t)b * TE * DD;
#pragma unroll
  for (int s = 0; s < 4; ++s) {
    int c = tid + 256 * s;
    int row = c >> 4, c4 = c & 15;
    float4 v = *(const float4*)(src + (size_t)(e0 + row) * DD + d0 + c4 * 4);
    uint32_t h0, l0, h1, l1, h2, l2, h3, l3;
    split2(v.x, h0, l0);
    split2(v.y, h1, l1);
    split2(v.z, h2, l2);
    split2(v.w, h3, l3);
    size_t o = (((size_t)b * TE + e0 + row) * DD + d0 + c4 * 4) >> 1;
    *(uint2*)&ehi[o] = make_uint2(h0 | (h1 << 16), h2 | (h3 << 16));
    *(uint2*)&elo[o] = make_uint2(l0 | (l1 << 16), l2 | (l3 << 16));
    TT[row][c4 * 4 + 0] = (uint16_t)h0;
    TT[row][c4 * 4 + 1] = (uint16_t)h1;
    TT[row][c4 * 4 + 2] = (uint16_t)h2;
    TT[row][c4 * 4 + 3] = (uint16_t)h3;
  }
  __syncthreads();
#pragma unroll
  for (int s = 0; s < 4; ++s) {
    int c = tid + 256 * s;
    int d = c >> 4, e4 = c & 15;
    uint32_t w0 = (uint32_t)TT[e4 * 4 + 0][d] | ((uint32_t)TT[e4 * 4 + 1][d] << 16);
    uint32_t w1 = (uint32_t)TT[e4 * 4 + 2][d] | ((uint32_t)TT[e4 * 4 + 3][d] << 16);
    *(uint2*)&eT[((size_t)b * DD + d0 + d) * TE + e0 + e4 * 4] = make_uint2(w0, w1);
  }
}

// ---------------------------------------------------------------------------
// K1 v2: S = dec @ enc^T with pre-split bf16 operands. Pure-MFMA loop:
// global_load_lds stages 4x [128][32] bf16 tiles, zero staging VALU.
// 3 MFMAs (AlBh + AhBl + AhBh) per fragment pair for fp32-class accuracy.
// S written fp32 to out[b,t,1024+e].
// ---------------------------------------------------------------------------
__global__ __launch_bounds__(256, 2)
void k1_scores_v2(const uint16_t* __restrict__ dhi, const uint16_t* __restrict__ dlo,
                  const uint16_t* __restrict__ ehi, const uint16_t* __restrict__ elo,
                  float* __restrict__ out) {
  __shared__ uint32_t AhU[2048], AlU[2048], BhU[2048], BlU[2048];
  const int tid = threadIdx.x;
  const int lane = tid & 63;
  const int wave = tid >> 6;
  const int wm = wave >> 1, wn = wave & 1;
  const int b = blockIdx.z;
  const int t0 = blockIdx.y * 128, e0 = blockIdx.x * 128;

  // staging chunk: tid -> row tid>>2 (64B rows = 4 chunks), col16 tid&3
  const int r2 = tid >> 2, c16 = tid & 3;
  const size_t abase = ((size_t)b * TD + t0 + r2) * DD + c16 * 8;
  const size_t bbase = ((size_t)b * TE + e0 + r2) * DD + c16 * 8;

  const int lr = lane & 15, q = lane >> 4;
  int aoff[4], boff[4];
#pragma unroll
  for (int i = 0; i < 4; ++i) {
    aoff[i] = (wm * 64 + i * 16 + lr) * 16 + q * 4;
    boff[i] = (wn * 64 + i * 16 + lr) * 16 + q * 4;
  }

  f32x4 acc[4][4] = {};

  for (int k0 = 0; k0 < DD; k0 += 32) {
    GLL16(dhi + abase + k0, (char*)AhU + tid * 16);
    GLL16(dhi + abase + k0 + 64 * DD, (char*)AhU + tid * 16 + 4096);
    GLL16(dlo + abase + k0, (char*)AlU + tid * 16);
    GLL16(dlo + abase + k0 + 64 * DD, (char*)AlU + tid * 16 + 4096);
    GLL16(ehi + bbase + k0, (char*)BhU + tid * 16);
    GLL16(ehi + bbase + k0 + 64 * DD, (char*)BhU + tid * 16 + 4096);
    GLL16(elo + bbase + k0, (char*)BlU + tid * 16);
    GLL16(elo + bbase + k0 + 64 * DD, (char*)BlU + tid * 16 + 4096);
    __syncthreads();  // compiler drains vmcnt(0) before s_barrier

    bf16x8 ah[4], al[4];
#pragma unroll
    for (int mi = 0; mi < 4; ++mi) {
      ah[mi] = *(const bf16x8*)&AhU[aoff[mi]];
      al[mi] = *(const bf16x8*)&AlU[aoff[mi]];
    }
#pragma unroll
    for (int ni = 0; ni < 4; ++ni) {
      bf16x8 bh = *(const bf16x8*)&BhU[boff[ni]];
      bf16x8 bl = *(const bf16x8*)&BlU[boff[ni]];
#pragma unroll
      for (int mi = 0; mi < 4; ++mi) {
        f32x4 c = acc[mi][ni];
        c = __builtin_amdgcn_mfma_f32_16x16x32_bf16(al[mi], bh, c, 0, 0, 0);
        c = __builtin_amdgcn_mfma_f32_16x16x32_bf16(ah[mi], bl, c, 0, 0, 0);
        c = __builtin_amdgcn_mfma_f32_16x16x32_bf16(ah[mi], bh, c, 0, 0, 0);
        acc[mi][ni] = c;
      }
    }
    __syncthreads();
  }

  // C/D layout: col(n=e) = lane&15, row(m=t) = (lane>>4)*4 + reg
  float* outb = out + (size_t)b * TD * 2048 + 1024;
  const int tb = t0 + wm * 64 + q * 4;
  const int eb = e0 + wn * 64 + lr;
#pragma unroll
  for (int mi = 0; mi < 4; ++mi)
#pragma unroll
    for (int ni = 0; ni < 4; ++ni)
#pragma unroll
      for (int i = 0; i < 4; ++i)
        outb[(size_t)(tb + mi * 16 + i) * 2048 + (eb + ni * 16)] = acc[mi][ni][i];
}

// ---------------------------------------------------------------------------
// K2 v2: softmax over e per (b,t) row; P (bf16) -> workspace; ALSO copies the
// decoder row into out[b,t,0:1024] (K4 fused — out first half is free now).
// ---------------------------------------------------------------------------
__global__ __launch_bounds__(256)
void k2_softmax_v2(const float* __restrict__ dec, float* __restrict__ out,
                   uint16_t* __restrict__ P) {
  const int lane = threadIdx.x & 63;
  const int row = blockIdx.x * 4 + (threadIdx.x >> 6);
  const float* Srow = out + (size_t)row * 2048 + 1024;
  float4 v[4];
#pragma unroll
  for (int s = 0; s < 4; ++s) v[s] = *(const float4*)(Srow + lane * 4 + s * 256);
  float m = -1e30f;
#pragma unroll
  for (int s = 0; s < 4; ++s)
    m = fmaxf(m, fmaxf(fmaxf(v[s].x, v[s].y), fmaxf(v[s].z, v[s].w)));
#pragma unroll
  for (int o = 32; o > 0; o >>= 1) m = fmaxf(m, __shfl_xor(m, o));
  float e[16];
  float sum = 0.f;
#pragma unroll
  for (int s = 0; s < 4; ++s) {
    e[4 * s + 0] = __expf(v[s].x - m);
    e[4 * s + 1] = __expf(v[s].y - m);
    e[4 * s + 2] = __expf(v[s].z - m);
    e[4 * s + 3] = __expf(v[s].w - m);
    sum += e[4 * s + 0] + e[4 * s + 1] + e[4 * s + 2] + e[4 * s + 3];
  }
#pragma unroll
  for (int o = 32; o > 0; o >>= 1) sum += __shfl_xor(sum, o);
  const float inv = 1.0f / sum;
  uint32_t* Prow = (uint32_t*)(P + (size_t)row * 1024);
#pragma unroll
  for (int s = 0; s < 4; ++s) {
    uint32_t r0 = rne_bf16(e[4 * s + 0] * inv);
    uint32_t r1 = rne_bf16(e[4 * s + 1] * inv);
    uint32_t r2 = rne_bf16(e[4 * s + 2] * inv);
    uint32_t r3 = rne_bf16(e[4 * s + 3] * inv);
    *(uint2*)&Prow[lane * 2 + s * 128] =
        make_uint2(r0 | (r1 << 16), r2 | (r3 << 16));
  }
  // fused dec copy (out first half never holds P anymore)
  const float4* d4 = (const float4*)(dec + (size_t)row * 1024);
  float4* o4 = (float4*)(out + (size_t)row * 2048);
#pragma unroll
  for (int s = 0; s < 4; ++s) o4[lane + s * 64] = d4[lane + s * 64];
}

// ---------------------------------------------------------------------------
// K3 v2: ctx[t][d] = sum_e P[t][e] * enc[e][d]. A = P bf16 (ws), B = encT bf16
// (pre-transposed in P0b). Both staged via global_load_lds — no transpose or
// conversion in the hot loop. Writes out[b,t,1024+d].
// ---------------------------------------------------------------------------
__global__ __launch_bounds__(256, 2)
void k3_av_v2(const uint16_t* __restrict__ P, const uint16_t* __restrict__ eT,
              float* __restrict__ out) {
  __shared__ uint32_t AU[2048], BU[2048];
  const int tid = threadIdx.x;
  const int lane = tid & 63, wave = tid >> 6;
  const int wm = wave >> 1, wn = wave & 1;
  const int b = blockIdx.z;
  const int t0 = blockIdx.y * 128, d0 = blockIdx.x * 128;
  const int r2 = tid >> 2, c16 = tid & 3;
  const size_t abase = ((size_t)b * TD + t0 + r2) * TE + c16 * 8;
  const size_t bbase = ((size_t)b * DD + d0 + r2) * TE + c16 * 8;
  const int lr = lane & 15, q = lane >> 4;
  int aoff[4], boff[4];
#pragma unroll
  for (int i = 0; i < 4; ++i) {
    aoff[i] = (wm * 64 + i * 16 + lr) * 16 + q * 4;
    boff[i] = (wn * 64 + i * 16 + lr) * 16 + q * 4;
  }
  f32x4 acc[4][4] = {};

  for (int e0k = 0; e0k < TE; e0k += 32) {
    GLL16(P + abase + e0k, (char*)AU + tid * 16);
    GLL16(P + abase + e0k + 64 * TE, (char*)AU + tid * 16 + 4096);
    GLL16(eT + bbase + e0k, (char*)BU + tid * 16);
    GLL16(eT + bbase + e0k + 64 * TE, (char*)BU + tid * 16 + 4096);
    __syncthreads();

    bf16x8 af[4];
#pragma unroll
    for (int mi = 0; mi < 4; ++mi) af[mi] = *(const bf16x8*)&AU[aoff[mi]];
#pragma unroll
    for (int ni = 0; ni < 4; ++ni) {
      bf16x8 bfr = *(const bf16x8*)&BU[boff[ni]];
#pragma unroll
      for (int mi = 0; mi < 4; ++mi)
        acc[mi][ni] =
            __builtin_amdgcn_mfma_f32_16x16x32_bf16(af[mi], bfr, acc[mi][ni], 0, 0, 0);
    }
    __syncthreads();
  }

  float* outb = out + (size_t)b * TD * 2048 + 1024;
  const int tb = t0 + wm * 64 + q * 4;
  const int db = d0 + wn * 64 + lr;
#pragma unroll
  for (int mi = 0; mi < 4; ++mi)
#pragma unroll
    for (int ni = 0; ni < 4; ++ni)
#pragma unroll
      for (int i = 0; i < 4; ++i)
        outb[(size_t)(tb + mi * 16 + i) * 2048 + (db + ni * 16)] = acc[mi][ni][i];
}

// ===========================================================================
// FALLBACK PATH (verified 443.3 µs pipeline) — used only if ws_size < 160 MiB.
// ===========================================================================
__global__ __launch_bounds__(256, 2)
void k1_scores(const float* __restrict__ dec, const float* __restrict__ enc,
               float* __restrict__ out) {
  __shared__ uint32_t AhU[2048], AlU[2048], BhU[2048], BlU[2048];
  const int tid = threadIdx.x;
  const int lane = tid & 63;
  const int wave = tid >> 6;
  const int wm = wave >> 1, wn = wave & 1;
  const int b = blockIdx.z;
  const int t0 = blockIdx.y * 128, e0 = blockIdx.x * 128;
  const float* A = dec + (size_t)b * TD * DD;
  const float* Bm = enc + (size_t)b * TE * DD;

  const int r = tid >> 3, c4 = tid & 7;
  const float* aptr = A + (size_t)(t0 + r) * DD + c4 * 4;
  const float* bptr = Bm + (size_t)(e0 + r) * DD + c4 * 4;

  const int lr = lane & 15, q = lane >> 4;
  int aoff[4], boff[4];
#pragma unroll
  for (int i = 0; i < 4; ++i) {
    aoff[i] = (wm * 64 + i * 16 + lr) * 16 + q * 4;
    boff[i] = (wn * 64 + i * 16 + lr) * 16 + q * 4;
  }

  f32x4 acc[4][4] = {};

  for (int k0 = 0; k0 < DD; k0 += 32) {
#pragma unroll
    for (int s = 0; s < 4; ++s) {
      const float4 va = *(const float4*)(aptr + (size_t)(32 * s) * DD);
      const float4 vb = *(const float4*)(bptr + (size_t)(32 * s) * DD);
      const int woff = (r + 32 * s) * 16 + c4 * 2;
      {
        uint32_t u0 = __builtin_bit_cast(uint32_t, va.x);
        uint32_t u1 = __builtin_bit_cast(uint32_t, va.y);
        uint32_t u2 = __builtin_bit_cast(uint32_t, va.z);
        uint32_t u3 = __builtin_bit_cast(uint32_t, va.w);
        uint32_t m0 = u0 & 0xFFFF0000u, m1 = u1 & 0xFFFF0000u;
        uint32_t m2 = u2 & 0xFFFF0000u, m3 = u3 & 0xFFFF0000u;
        float l0 = va.x - __builtin_bit_cast(float, m0);
        float l1 = va.y - __builtin_bit_cast(float, m1);
        float l2 = va.z - __builtin_bit_cast(float, m2);
        float l3 = va.w - __builtin_bit_cast(float, m3);
        *(uint2*)&AhU[woff] = make_uint2((m0 >> 16) | m1, (m2 >> 16) | m3);
        *(uint2*)&AlU[woff] = make_uint2(
            (__builtin_bit_cast(uint32_t, l0) >> 16) |
                (__builtin_bit_cast(uint32_t, l1) & 0xFFFF0000u),
            (__builtin_bit_cast(uint32_t, l2) >> 16) |
                (__builtin_bit_cast(uint32_t, l3) & 0xFFFF0000u));
      }
      {
        uint32_t u0 = __builtin_bit_cast(uint32_t, vb.x);
        uint32_t u1 = __builtin_bit_cast(uint32_t, vb.y);
        uint32_t u2 = __builtin_bit_cast(uint32_t, vb.z);
        uint32_t u3 = __builtin_bit_cast(uint32_t, vb.w);
        uint32_t m0 = u0 & 0xFFFF0000u, m1 = u1 & 0xFFFF0000u;
        uint32_t m2 = u2 & 0xFFFF0000u, m3 = u3 & 0xFFFF0000u;
        float l0 = vb.x - __builtin_bit_cast(float, m0);
        float l1 = vb.y - __builtin_bit_cast(float, m1);
        float l2 = vb.z - __builtin_bit_cast(float, m2);
        float l3 = vb.w - __builtin_bit_cast(float, m3);
        *(uint2*)&BhU[woff] = make_uint2((m0 >> 16) | m1, (m2 >> 16) | m3);
        *(uint2*)&BlU[woff] = make_uint2(
            (__builtin_bit_cast(uint32_t, l0) >> 16) |
                (__builtin_bit_cast(uint32_t, l1) & 0xFFFF0000u),
            (__builtin_bit_cast(uint32_t, l2) >> 16) |
                (__builtin_bit_cast(uint32_t, l3) & 0xFFFF0000u));
      }
    }
    __syncthreads();

    bf16x8 ah[4], al[4];
#pragma unroll
    for (int mi = 0; mi < 4; ++mi) {
      ah[mi] = *(const bf16x8*)&AhU[aoff[mi]];
      al[mi] = *(const bf16x8*)&AlU[aoff[mi]];
    }
#pragma unroll
    for (int ni = 0; ni < 4; ++ni) {
      bf16x8 bh = *(const bf16x8*)&BhU[boff[ni]];
      bf16x8 bl = *(const bf16x8*)&BlU[boff[ni]];
#pragma unroll
      for (int mi = 0; mi < 4; ++mi) {
        f32x4 c = acc[mi][ni];
        c = __builtin_amdgcn_mfma_f32_16x16x32_bf16(al[mi], bh, c, 0, 0, 0);
        c = __builtin_amdgcn_mfma_f32_16x16x32_bf16(ah[mi], bl, c, 0, 0, 0);
        c = __builtin_amdgcn_mfma_f32_16x16x32_bf16(ah[mi], bh, c, 0, 0, 0);
        acc[mi][ni] = c;
      }
    }
    __syncthreads();
    aptr += 32;
    bptr += 32;
  }

  float* outb = out + (size_t)b * TD * 2048 + 1024;
  const int tb = t0 + wm * 64 + q * 4;
  const int eb = e0 + wn * 64 + lr;
#pragma unroll
  for (int mi = 0; mi < 4; ++mi)
#pragma unroll
    for (int ni = 0; ni < 4; ++ni)
#pragma unroll
      for (int i = 0; i < 4; ++i)
        outb[(size_t)(tb + mi * 16 + i) * 2048 + (eb + ni * 16)] = acc[mi][ni][i];
}

__global__ __launch_bounds__(256)
void k2_softmax(float* out) {
  const int lane = threadIdx.x & 63;
  const int row = blockIdx.x * 4 + (threadIdx.x >> 6);
  float* Srow = out + (size_t)row * 2048 + 1024;
  float4 v[4];
#pragma unroll
  for (int s = 0; s < 4; ++s) v[s] = *(const float4*)(Srow + lane * 4 + s * 256);
  float m = -1e30f;
#pragma unroll
  for (int s = 0; s < 4; ++s)
    m = fmaxf(m, fmaxf(fmaxf(v[s].x, v[s].y), fmaxf(v[s].z, v[s].w)));
#pragma unroll
  for (int o = 32; o > 0; o >>= 1) m = fmaxf(m, __shfl_xor(m, o));
  float e[16];
  float sum = 0.f;
#pragma unroll
  for (int s = 0; s < 4; ++s) {
    e[4 * s + 0] = __expf(v[s].x - m);
    e[4 * s + 1] = __expf(v[s].y - m);
    e[4 * s + 2] = __expf(v[s].z - m);
    e[4 * s + 3] = __expf(v[s].w - m);
    sum += e[4 * s + 0] + e[4 * s + 1] + e[4 * s + 2] + e[4 * s + 3];
  }
#pragma unroll
  for (int o = 32; o > 0; o >>= 1) sum += __shfl_xor(sum, o);
  const float inv = 1.0f / sum;
  uint32_t* Prow = (uint32_t*)(out + (size_t)row * 2048);
#pragma unroll
  for (int s = 0; s < 4; ++s) {
    uint32_t r0 = rne_bf16(e[4 * s + 0] * inv);
    uint32_t r1 = rne_bf16(e[4 * s + 1] * inv);
    uint32_t r2 = rne_bf16(e[4 * s + 2] * inv);
    uint32_t r3 = rne_bf16(e[4 * s + 3] * inv);
    *(uint2*)&Prow[lane * 2 + s * 128] =
        make_uint2(r0 | (r1 << 16), r2 | (r3 << 16));
  }
}

__global__ __launch_bounds__(256, 2)
void k3_av(const float* __restrict__ enc, float* __restrict__ out) {
  __shared__ uint32_t AU[2048];
  __shared__ uint32_t BtU[128 * 20];
  const int tid = threadIdx.x;
  const int lane = tid & 63, wave = tid >> 6;
  const int wm = wave >> 1, wn = wave & 1;
  const int b = blockIdx.z;
  const int t0 = blockIdx.y * 128, d0 = blockIdx.x * 128;
  const float* V = enc + (size_t)b * TE * DD;
  const uint16_t* Pb = (const uint16_t*)(out + (size_t)b * TD * 2048);
  const int lr = lane & 15, q = lane >> 4;
  int aoff[4], boff[4];
#pragma unroll
  for (int i = 0; i < 4; ++i) {
    aoff[i] = (wm * 64 + i * 16 + lr) * 16 + q * 4;
    boff[i] = (wn * 64 + i * 16 + lr) * 20 + q * 4;
  }
  const int dB = tid & 127;
  f32x4 acc[4][4] = {};

  for (int e0k = 0; e0k < TE; e0k += 32) {
#pragma unroll
    for (int s = 0; s < 2; ++s) {
      int c = tid + 256 * s;
      int rc = c >> 2, cc = c & 3;
      uint4 va = *(const uint4*)(Pb + (size_t)(t0 + rc) * 4096 + e0k + cc * 8);
      *(uint4*)&AU[c * 4] = va;
    }
#pragma unroll
    for (int s = 0; s < 4; ++s) {
      int eg = (tid >> 7) + 2 * s;
      const float* src = V + (size_t)(e0k + eg * 4) * DD + d0 + dB;
      float x0 = src[0], x1 = src[DD], x2 = src[2 * DD], x3 = src[3 * DD];
      uint32_t r0 = rne_bf16(x0), r1 = rne_bf16(x1);
      uint32_t r2 = rne_bf16(x2), r3 = rne_bf16(x3);
      *(uint2*)&BtU[dB * 20 + eg * 2] =
          make_uint2(r0 | (r1 << 16), r2 | (r3 << 16));
    }
    __syncthreads();

    bf16x8 af[4];
#pragma unroll
    for (int mi = 0; mi < 4; ++mi) af[mi] = *(const bf16x8*)&AU[aoff[mi]];
#pragma unroll
    for (int ni = 0; ni < 4; ++ni) {
      bf16x8 bfr = *(const bf16x8*)&BtU[boff[ni]];
#pragma unroll
      for (int mi = 0; mi < 4; ++mi)
        acc[mi][ni] =
            __builtin_amdgcn_mfma_f32_16x16x32_bf16(af[mi], bfr, acc[mi][ni], 0, 0, 0);
    }
    __syncthreads();
  }

  float* outb = out + (size_t)b * TD * 2048 + 1024;
  const int tb = t0 + wm * 64 + q * 4;
  const int db = d0 + wn * 64 + lr;
#pragma unroll
  for (int mi = 0; mi < 4; ++mi)
#pragma unroll
    for (int ni = 0; ni < 4; ++ni)
#pragma unroll
      for (int i = 0; i < 4; ++i)
        outb[(size_t)(tb + mi * 16 + i) * 2048 + (db + ni * 16)] = acc[mi][ni][i];
}

__global__ __launch_bounds__(256)
void k4_copydec(const float4* __restrict__ dec4, float4* __restrict__ out4) {
  size_t g = (size_t)blockIdx.x * 512 + threadIdx.x;
#pragma unroll
  for (int s = 0; s < 2; ++s, g += 256) {
    size_t row = g >> 8, col = g & 255;
    out4[row * 512 + col] = dec4[g];
  }
}

extern "C" void kernel_launch(void* const* d_in, const int* in_sizes, int n_in,
                              void* d_out, int out_size, void* d_ws, size_t ws_size,
                              hipStream_t stream) {
  // setup_inputs order: [0]=encoder_outputs, [1]=decoder_outputs (fp32)
  const float* enc = (const float*)d_in[0];
  const float* dec = (const float*)d_in[1];
  float* out = (float*)d_out;

  const size_t M32 = 32ull << 20;  // 32 MiB per bf16 tensor
  if (d_ws != nullptr && ws_size >= 5 * M32) {
    char* ws = (char*)d_ws;
    uint16_t* dhi = (uint16_t*)(ws);
    uint16_t* dlo = (uint16_t*)(ws + M32);
    uint16_t* ehi = (uint16_t*)(ws + 2 * M32);
    uint16_t* elo = (uint16_t*)(ws + 3 * M32);
    uint16_t* eT = (uint16_t*)(ws + 4 * M32);
    uint16_t* P = dhi;  // dec_hi region is dead after K1; reuse for P

    hipLaunchKernelGGL(p0a_split_dec, dim3(2048), dim3(256), 0, stream,
                       (const float4*)dec, (uint32_t*)dhi, (uint32_t*)dlo);
    hipLaunchKernelGGL(p0b_split_enc, dim3(256, 1, 16), dim3(256), 0, stream,
                       enc, (uint32_t*)ehi, (uint32_t*)elo, eT);
    hipLaunchKernelGGL(k1_scores_v2, dim3(8, 8, 16), dim3(256), 0, stream,
                       dhi, dlo, ehi, elo, out);
    hipLaunchKernelGGL(k2_softmax_v2, dim3(4096), dim3(256), 0, stream, dec, out, P);
    hipLaunchKernelGGL(k3_av_v2, dim3(8, 8, 16), dim3(256), 0, stream, P, eT, out);
  } else {
    // fallback: verified pipeline (no workspace required)
    hipLaunchKernelGGL(k1_scores, dim3(8, 8, 16), dim3(256), 0, stream, dec, enc, out);
    hipLaunchKernelGGL(k2_softmax, dim3(4096), dim3(256), 0, stream, out);
    hipLaunchKernelGGL(k3_av, dim3(8, 8, 16), dim3(256), 0, stream, enc, out);
    hipLaunchKernelGGL(k4_copydec, dim3(8192), dim3(256), 0, stream,
                       (const float4*)dec, (float4*)out);
  }
}

// Round 2
// 415.990 us; speedup vs baseline: 1.1129x; 1.1129x over previous
//
#include <hip/hip_runtime.h>
#include <hip/hip_bf16.h>
#include <stdint.h>

typedef __bf16 bf16x8 __attribute__((ext_vector_type(8)));
typedef float f32x4 __attribute__((ext_vector_type(4)));

#define B_DIM 16
#define TD 1024
#define TE 1024
#define DD 1024

typedef __attribute__((address_space(1))) void as1_void;
typedef __attribute__((address_space(3))) void as3_void;

// global -> LDS direct copy, 16B per lane. LDS dest must be linear in lane order.
#define GLL16(gp, lp) \
  __builtin_amdgcn_global_load_lds((as1_void*)(gp), (as3_void*)(lp), 16, 0, 0)

#define SB __builtin_amdgcn_sched_barrier(0)
#define BAR()                      \
  do {                             \
    SB;                            \
    __builtin_amdgcn_s_barrier();  \
    SB;                            \
  } while (0)
#define VMW2()                                       \
  do {                                               \
    asm volatile("s_waitcnt vmcnt(2)" ::: "memory"); \
    SB;                                              \
  } while (0)

__device__ __forceinline__ uint32_t rne_bf16(float x) {
  uint32_t u = __builtin_bit_cast(uint32_t, x);
  return (u + 0x7FFFu + ((u >> 16) & 1u)) >> 16;
}

// RNE two-term split: x ~= hi + lo, both bf16.
__device__ __forceinline__ void split2(float x, uint32_t& hi, uint32_t& lo) {
  uint32_t h = rne_bf16(x);
  float hf = __builtin_bit_cast(float, h << 16);
  hi = h;
  lo = rne_bf16(x - hf);
}

// ---------------------------------------------------------------------------
// P0a: dec fp32 -> dec_hi, dec_lo bf16 (each element split exactly once).
// ---------------------------------------------------------------------------
__global__ __launch_bounds__(256)
void p0a_split_dec(const float4* __restrict__ dec4, uint32_t* __restrict__ dhi,
                   uint32_t* __restrict__ dlo) {
  size_t g = (size_t)blockIdx.x * 256 + threadIdx.x;
#pragma unroll
  for (int s = 0; s < 8; ++s, g += 524288) {
    float4 v = dec4[g];
    uint32_t h0, l0, h1, l1, h2, l2, h3, l3;
    split2(v.x, h0, l0);
    split2(v.y, h1, l1);
    split2(v.z, h2, l2);
    split2(v.w, h3, l3);
    *(uint2*)&dhi[g * 2] = make_uint2(h0 | (h1 << 16), h2 | (h3 << 16));
    *(uint2*)&dlo[g * 2] = make_uint2(l0 | (l1 << 16), l2 | (l3 << 16));
  }
}

// ---------------------------------------------------------------------------
// P0b: enc fp32 -> enc_hi, enc_lo bf16 [b][e][d], plus encT bf16 [b][d][e].
// ---------------------------------------------------------------------------
__global__ __launch_bounds__(256)
void p0b_split_enc(const float* __restrict__ enc, uint32_t* __restrict__ ehi,
                   uint32_t* __restrict__ elo, uint16_t* __restrict__ eT) {
  __shared__ uint16_t TT[64][65];
  const int tid = threadIdx.x;
  const int b = blockIdx.z;
  const int d0 = (blockIdx.x & 15) * 64, e0 = (blockIdx.x >> 4) * 64;
  const float* src = enc + (size_t)b * TE * DD;
#pragma unroll
  for (int s = 0; s < 4; ++s) {
    int c = tid + 256 * s;
    int row = c >> 4, c4 = c & 15;
    float4 v = *(const float4*)(src + (size_t)(e0 + row) * DD + d0 + c4 * 4);
    uint32_t h0, l0, h1, l1, h2, l2, h3, l3;
    split2(v.x, h0, l0);
    split2(v.y, h1, l1);
    split2(v.z, h2, l2);
    split2(v.w, h3, l3);
    size_t o = (((size_t)b * TE + e0 + row) * DD + d0 + c4 * 4) >> 1;
    *(uint2*)&ehi[o] = make_uint2(h0 | (h1 << 16), h2 | (h3 << 16));
    *(uint2*)&elo[o] = make_uint2(l0 | (l1 << 16), l2 | (l3 << 16));
    TT[row][c4 * 4 + 0] = (uint16_t)h0;
    TT[row][c4 * 4 + 1] = (uint16_t)h1;
    TT[row][c4 * 4 + 2] = (uint16_t)h2;
    TT[row][c4 * 4 + 3] = (uint16_t)h3;
  }
  __syncthreads();
#pragma unroll
  for (int s = 0; s < 4; ++s) {
    int c = tid + 256 * s;
    int d = c >> 4, e4 = c & 15;
    uint32_t w0 = (uint32_t)TT[e4 * 4 + 0][d] | ((uint32_t)TT[e4 * 4 + 1][d] << 16);
    uint32_t w1 = (uint32_t)TT[e4 * 4 + 2][d] | ((uint32_t)TT[e4 * 4 + 3][d] << 16);
    *(uint2*)&eT[((size_t)b * DD + d0 + d) * TE + e0 + e4 * 4] = make_uint2(w0, w1);
  }
}

// ---------------------------------------------------------------------------
// 256x256-tile 8-phase bf16 GEMM (HK-style schedule, plain HIP).
//   C[m][n] = sum_seg sum_k A_seg[m][k] * B_seg[n][k],  K'=NSEG*1024
//   A_seg/B_seg row-major [1024][1024] bf16 per batch (batch stride 1M elems).
//   out: fp32 at out[b, m, 1024 + n]  (row stride 2048).
// Geometry: BK=64, 512 thr = 8 waves (2M x 4N), per-wave C = 128x64.
// LDS 128 KiB dynamic: [buf2][op2][half2][128 rows][128 B].
// Swizzle: byte col ^= (row&7)<<4, applied via pre-swizzled global source
// (linear global_load_lds dest) and re-applied on ds_read addresses.
// Schedule per K-tile t (4 phases, quadrants (kk,npair)):
//   ph1 (0,0): read Akk0+Bn01kk0 ; stage B0(t+1)->nxt
//   ph2 (0,1): read Bn23kk0      ; stage A1(t+1)->nxt
//   ph3 (1,1): read Akk1+Bn23kk1 ; stage B1(t+1)->nxt
//   ph4 (1,0): read Bn01kk1      ; stage A0(t+2)->cur ; vmcnt(2)
// Each phase: reads/stages -> barrier -> setprio1 -> 16 MFMA -> setprio0 -> barrier.
// vmcnt(2) proof: per tile 8 loads issued; at tile-end wait, the only 2 allowed
// in flight are A0(t+2)'s, so all 4 half-tiles of t+1 have landed. Never drains to 0.
// ---------------------------------------------------------------------------
template <int NSEG>
__global__ __launch_bounds__(512, 2)
void k_gemm256(const uint16_t* __restrict__ a0, const uint16_t* __restrict__ a1,
               const uint16_t* __restrict__ a2, const uint16_t* __restrict__ b0,
               const uint16_t* __restrict__ b1, const uint16_t* __restrict__ b2,
               float* __restrict__ out) {
  extern __shared__ char lds[];
  const int tid = threadIdx.x;
  const int lane = tid & 63, wave = tid >> 6;
  const int wr = wave >> 2, wc = wave & 3;
  const int lr = lane & 15, q = lane >> 4;

  // XCD-bijective swizzle (256 blocks, 8 XCDs, 32 per chunk)
  const int id = blockIdx.x;
  const int swz = (id & 7) * 32 + (id >> 3);
  const int b = swz >> 4, mblk = (swz >> 2) & 3, nblk = swz & 3;
  const size_t bOff = (size_t)b << 20;
  const uint16_t* As[3] = {a0 + bOff, a1 + bOff, a2 + bOff};
  const uint16_t* Bs[3] = {b0 + bOff, b1 + bOff, b2 + bOff};
  const int mrow0 = mblk * 256, nrow0 = nblk * 256;
  constexpr int T = NSEG * 16;

  f32x4 acc[8][4] = {};
  bf16x8 a[8], bA[2], bB[2];

  // stage one half-tile (128 rows x 64 k) of op (0=A,1=B), K-tile tau, into buf
  auto STAGE = [&](int op, int half, int tau, int buf) {
    int seg, klt;
    if constexpr (NSEG == 3) {
      seg = tau >> 4;
      klt = tau & 15;
    } else {
      seg = 0;
      klt = tau;
    }
    const uint16_t* base = (op == 0 ? As[seg] : Bs[seg]) +
                           (size_t)((op == 0 ? mrow0 : nrow0) + half * 128) * 1024 +
                           klt * 64;
    char* dst = lds + (((buf * 2 + op) * 2 + half) << 14);
#pragma unroll
    for (int j = 0; j < 2; ++j) {
      int chunk = j * 512 + tid;
      int row = chunk >> 3;
      int k8 = ((chunk & 7) ^ (row & 7)) << 3;  // inverse-swizzled source k
      GLL16(base + (size_t)row * 1024 + k8, dst + chunk * 16);
    }
  };

  auto LDA = [&](int kk, int buf) {
    const char* src = lds + (((buf * 2 + 0) * 2 + wr) << 14);
#pragma unroll
    for (int mi = 0; mi < 8; ++mi) {
      int rl = mi * 16 + lr;
      int col = (kk * 64 + q * 16) ^ ((rl & 7) << 4);
      a[mi] = *(const bf16x8*)(src + rl * 128 + col);
    }
  };
  auto LDB = [&](int kk, int nbase, bf16x8* bb, int buf) {
    const char* src = lds + (((buf * 2 + 1) * 2 + (wc >> 1)) << 14);
#pragma unroll
    for (int u = 0; u < 2; ++u) {
      int rl = (wc & 1) * 64 + (nbase + u) * 16 + lr;
      int col = (kk * 64 + q * 16) ^ ((rl & 7) << 4);
      bb[u] = *(const bf16x8*)(src + rl * 128 + col);
    }
  };
  auto MFMAQ = [&](bf16x8* bb, int npair) {
#pragma unroll
    for (int u = 0; u < 2; ++u)
#pragma unroll
      for (int mi = 0; mi < 8; ++mi)
        acc[mi][npair * 2 + u] = __builtin_amdgcn_mfma_f32_16x16x32_bf16(
            a[mi], bb[u], acc[mi][npair * 2 + u], 0, 0, 0);
  };

  // prologue: tile0's 4 half-tiles + A0(1); leave A0(1) in flight
  STAGE(0, 0, 0, 0);
  STAGE(1, 0, 0, 0);
  STAGE(0, 1, 0, 0);
  STAGE(1, 1, 0, 0);
  STAGE(0, 0, 1, 1);
  VMW2();
  BAR();

  for (int t = 0; t < T; ++t) {
    const int cur = t & 1, nxt = cur ^ 1;
    const int t1 = (t + 1 < T) ? t + 1 : 0;
    const int t2 = (t + 2 < T) ? t + 2 : t + 2 - T;
    // ---- phase 1: quadrant (kk=0, npair=0)
    LDA(0, cur);
    LDB(0, 0, bA, cur);
    STAGE(1, 0, t1, nxt);
    BAR();
    __builtin_amdgcn_s_setprio(1);
    MFMAQ(bA, 0);
    __builtin_amdgcn_s_setprio(0);
    BAR();
    // ---- phase 2: (0, 1)
    LDB(0, 2, bB, cur);
    STAGE(0, 1, t1, nxt);
    BAR();
    __builtin_amdgcn_s_setprio(1);
    MFMAQ(bB, 1);
    __builtin_amdgcn_s_setprio(0);
    BAR();
    // ---- phase 3: (1, 1)
    LDA(1, cur);
    LDB(1, 2, bB, cur);
    STAGE(1, 1, t1, nxt);
    BAR();
    __builtin_amdgcn_s_setprio(1);
    MFMAQ(bB, 1);
    __builtin_amdgcn_s_setprio(0);
    BAR();
    // ---- phase 4: (1, 0)
    LDB(1, 0, bA, cur);
    STAGE(0, 0, t2, cur);  // (t+2)&1 == cur; A-area of cur is dead after ph3
    VMW2();
    BAR();
    __builtin_amdgcn_s_setprio(1);
    MFMAQ(bA, 0);
    __builtin_amdgcn_s_setprio(0);
    BAR();
  }

  // epilogue: C/D layout col = lane&15, row = (lane>>4)*4 + reg
  float* outp = out + (size_t)b * TD * 2048 + 1024;
  const int m0 = mrow0 + wr * 128 + q * 4;
  const int n0 = nrow0 + wc * 64 + lr;
#pragma unroll
  for (int mi = 0; mi < 8; ++mi)
#pragma unroll
    for (int ni = 0; ni < 4; ++ni)
#pragma unroll
      for (int i = 0; i < 4; ++i)
        outp[(size_t)(m0 + mi * 16 + i) * 2048 + (n0 + ni * 16)] = acc[mi][ni][i];
}

// ---------------------------------------------------------------------------
// K2 v2: softmax over e per (b,t) row; P (bf16) -> workspace; also copies the
// decoder row into out[b,t,0:1024].
// ---------------------------------------------------------------------------
__global__ __launch_bounds__(256)
void k2_softmax_v2(const float* __restrict__ dec, float* __restrict__ out,
                   uint16_t* __restrict__ P) {
  const int lane = threadIdx.x & 63;
  const int row = blockIdx.x * 4 + (threadIdx.x >> 6);
  const float* Srow = out + (size_t)row * 2048 + 1024;
  float4 v[4];
#pragma unroll
  for (int s = 0; s < 4; ++s) v[s] = *(const float4*)(Srow + lane * 4 + s * 256);
  float m = -1e30f;
#pragma unroll
  for (int s = 0; s < 4; ++s)
    m = fmaxf(m, fmaxf(fmaxf(v[s].x, v[s].y), fmaxf(v[s].z, v[s].w)));
#pragma unroll
  for (int o = 32; o > 0; o >>= 1) m = fmaxf(m, __shfl_xor(m, o));
  float e[16];
  float sum = 0.f;
#pragma unroll
  for (int s = 0; s < 4; ++s) {
    e[4 * s + 0] = __expf(v[s].x - m);
    e[4 * s + 1] = __expf(v[s].y - m);
    e[4 * s + 2] = __expf(v[s].z - m);
    e[4 * s + 3] = __expf(v[s].w - m);
    sum += e[4 * s + 0] + e[4 * s + 1] + e[4 * s + 2] + e[4 * s + 3];
  }
#pragma unroll
  for (int o = 32; o > 0; o >>= 1) sum += __shfl_xor(sum, o);
  const float inv = 1.0f / sum;
  uint32_t* Prow = (uint32_t*)(P + (size_t)row * 1024);
#pragma unroll
  for (int s = 0; s < 4; ++s) {
    uint32_t r0 = rne_bf16(e[4 * s + 0] * inv);
    uint32_t r1 = rne_bf16(e[4 * s + 1] * inv);
    uint32_t r2 = rne_bf16(e[4 * s + 2] * inv);
    uint32_t r3 = rne_bf16(e[4 * s + 3] * inv);
    *(uint2*)&Prow[lane * 2 + s * 128] =
        make_uint2(r0 | (r1 << 16), r2 | (r3 << 16));
  }
  const float4* d4 = (const float4*)(dec + (size_t)row * 1024);
  float4* o4 = (float4*)(out + (size_t)row * 2048);
#pragma unroll
  for (int s = 0; s < 4; ++s) o4[lane + s * 64] = d4[lane + s * 64];
}

// ===========================================================================
// FALLBACK PATH (verified pipeline) — used if workspace/LDS attr unavailable.
// ===========================================================================
__global__ __launch_bounds__(256, 2)
void k1_scores(const float* __restrict__ dec, const float* __restrict__ enc,
               float* __restrict__ out) {
  __shared__ uint32_t AhU[2048], AlU[2048], BhU[2048], BlU[2048];
  const int tid = threadIdx.x;
  const int lane = tid & 63;
  const int wave = tid >> 6;
  const int wm = wave >> 1, wn = wave & 1;
  const int b = blockIdx.z;
  const int t0 = blockIdx.y * 128, e0 = blockIdx.x * 128;
  const float* A = dec + (size_t)b * TD * DD;
  const float* Bm = enc + (size_t)b * TE * DD;

  const int r = tid >> 3, c4 = tid & 7;
  const float* aptr = A + (size_t)(t0 + r) * DD + c4 * 4;
  const float* bptr = Bm + (size_t)(e0 + r) * DD + c4 * 4;

  const int lr = lane & 15, q = lane >> 4;
  int aoff[4], boff[4];
#pragma unroll
  for (int i = 0; i < 4; ++i) {
    aoff[i] = (wm * 64 + i * 16 + lr) * 16 + q * 4;
    boff[i] = (wn * 64 + i * 16 + lr) * 16 + q * 4;
  }

  f32x4 acc[4][4] = {};

  for (int k0 = 0; k0 < DD; k0 += 32) {
#pragma unroll
    for (int s = 0; s < 4; ++s) {
      const float4 va = *(const float4*)(aptr + (size_t)(32 * s) * DD);
      const float4 vb = *(const float4*)(bptr + (size_t)(32 * s) * DD);
      const int woff = (r + 32 * s) * 16 + c4 * 2;
      {
        uint32_t u0 = __builtin_bit_cast(uint32_t, va.x);
        uint32_t u1 = __builtin_bit_cast(uint32_t, va.y);
        uint32_t u2 = __builtin_bit_cast(uint32_t, va.z);
        uint32_t u3 = __builtin_bit_cast(uint32_t, va.w);
        uint32_t m0 = u0 & 0xFFFF0000u, m1 = u1 & 0xFFFF0000u;
        uint32_t m2 = u2 & 0xFFFF0000u, m3 = u3 & 0xFFFF0000u;
        float l0 = va.x - __builtin_bit_cast(float, m0);
        float l1 = va.y - __builtin_bit_cast(float, m1);
        float l2 = va.z - __builtin_bit_cast(float, m2);
        float l3 = va.w - __builtin_bit_cast(float, m3);
        *(uint2*)&AhU[woff] = make_uint2((m0 >> 16) | m1, (m2 >> 16) | m3);
        *(uint2*)&AlU[woff] = make_uint2(
            (__builtin_bit_cast(uint32_t, l0) >> 16) |
                (__builtin_bit_cast(uint32_t, l1) & 0xFFFF0000u),
            (__builtin_bit_cast(uint32_t, l2) >> 16) |
                (__builtin_bit_cast(uint32_t, l3) & 0xFFFF0000u));
      }
      {
        uint32_t u0 = __builtin_bit_cast(uint32_t, vb.x);
        uint32_t u1 = __builtin_bit_cast(uint32_t, vb.y);
        uint32_t u2 = __builtin_bit_cast(uint32_t, vb.z);
        uint32_t u3 = __builtin_bit_cast(uint32_t, vb.w);
        uint32_t m0 = u0 & 0xFFFF0000u, m1 = u1 & 0xFFFF0000u;
        uint32_t m2 = u2 & 0xFFFF0000u, m3 = u3 & 0xFFFF0000u;
        float l0 = vb.x - __builtin_bit_cast(float, m0);
        float l1 = vb.y - __builtin_bit_cast(float, m1);
        float l2 = vb.z - __builtin_bit_cast(float, m2);
        float l3 = vb.w - __builtin_bit_cast(float, m3);
        *(uint2*)&BhU[woff] = make_uint2((m0 >> 16) | m1, (m2 >> 16) | m3);
        *(uint2*)&BlU[woff] = make_uint2(
            (__builtin_bit_cast(uint32_t, l0) >> 16) |
                (__builtin_bit_cast(uint32_t, l1) & 0xFFFF0000u),
            (__builtin_bit_cast(uint32_t, l2) >> 16) |
                (__builtin_bit_cast(uint32_t, l3) & 0xFFFF0000u));
      }
    }
    __syncthreads();

    bf16x8 ah[4], al[4];
#pragma unroll
    for (int mi = 0; mi < 4; ++mi) {
      ah[mi] = *(const bf16x8*)&AhU[aoff[mi]];
      al[mi] = *(const bf16x8*)&AlU[aoff[mi]];
    }
#pragma unroll
    for (int ni = 0; ni < 4; ++ni) {
      bf16x8 bh = *(const bf16x8*)&BhU[boff[ni]];
      bf16x8 bl = *(const bf16x8*)&BlU[boff[ni]];
#pragma unroll
      for (int mi = 0; mi < 4; ++mi) {
        f32x4 c = acc[mi][ni];
        c = __builtin_amdgcn_mfma_f32_16x16x32_bf16(al[mi], bh, c, 0, 0, 0);
        c = __builtin_amdgcn_mfma_f32_16x16x32_bf16(ah[mi], bl, c, 0, 0, 0);
        c = __builtin_amdgcn_mfma_f32_16x16x32_bf16(ah[mi], bh, c, 0, 0, 0);
        acc[mi][ni] = c;
      }
    }
    __syncthreads();
    aptr += 32;
    bptr += 32;
  }

  float* outb = out + (size_t)b * TD * 2048 + 1024;
  const int tb = t0 + wm * 64 + q * 4;
  const int eb = e0 + wn * 64 + lr;
#pragma unroll
  for (int mi = 0; mi < 4; ++mi)
#pragma unroll
    for (int ni = 0; ni < 4; ++ni)
#pragma unroll
      for (int i = 0; i < 4; ++i)
        outb[(size_t)(tb + mi * 16 + i) * 2048 + (eb + ni * 16)] = acc[mi][ni][i];
}

__global__ __launch_bounds__(256)
void k2_softmax(float* out) {
  const int lane = threadIdx.x & 63;
  const int row = blockIdx.x * 4 + (threadIdx.x >> 6);
  float* Srow = out + (size_t)row * 2048 + 1024;
  float4 v[4];
#pragma unroll
  for (int s = 0; s < 4; ++s) v[s] = *(const float4*)(Srow + lane * 4 + s * 256);
  float m = -1e30f;
#pragma unroll
  for (int s = 0; s < 4; ++s)
    m = fmaxf(m, fmaxf(fmaxf(v[s].x, v[s].y), fmaxf(v[s].z, v[s].w)));
#pragma unroll
  for (int o = 32; o > 0; o >>= 1) m = fmaxf(m, __shfl_xor(m, o));
  float e[16];
  float sum = 0.f;
#pragma unroll
  for (int s = 0; s < 4; ++s) {
    e[4 * s + 0] = __expf(v[s].x - m);
    e[4 * s + 1] = __expf(v[s].y - m);
    e[4 * s + 2] = __expf(v[s].z - m);
    e[4 * s + 3] = __expf(v[s].w - m);
    sum += e[4 * s + 0] + e[4 * s + 1] + e[4 * s + 2] + e[4 * s + 3];
  }
#pragma unroll
  for (int o = 32; o > 0; o >>= 1) sum += __shfl_xor(sum, o);
  const float inv = 1.0f / sum;
  uint32_t* Prow = (uint32_t*)(out + (size_t)row * 2048);
#pragma unroll
  for (int s = 0; s < 4; ++s) {
    uint32_t r0 = rne_bf16(e[4 * s + 0] * inv);
    uint32_t r1 = rne_bf16(e[4 * s + 1] * inv);
    uint32_t r2 = rne_bf16(e[4 * s + 2] * inv);
    uint32_t r3 = rne_bf16(e[4 * s + 3] * inv);
    *(uint2*)&Prow[lane * 2 + s * 128] =
        make_uint2(r0 | (r1 << 16), r2 | (r3 << 16));
  }
}

__global__ __launch_bounds__(256, 2)
void k3_av(const float* __restrict__ enc, float* __restrict__ out) {
  __shared__ uint32_t AU[2048];
  __shared__ uint32_t BtU[128 * 20];
  const int tid = threadIdx.x;
  const int lane = tid & 63, wave = tid >> 6;
  const int wm = wave >> 1, wn = wave & 1;
  const int b = blockIdx.z;
  const int t0 = blockIdx.y * 128, d0 = blockIdx.x * 128;
  const float* V = enc + (size_t)b * TE * DD;
  const uint16_t* Pb = (const uint16_t*)(out + (size_t)b * TD * 2048);
  const int lr = lane & 15, q = lane >> 4;
  int aoff[4], boff[4];
#pragma unroll
  for (int i = 0; i < 4; ++i) {
    aoff[i] = (wm * 64 + i * 16 + lr) * 16 + q * 4;
    boff[i] = (wn * 64 + i * 16 + lr) * 20 + q * 4;
  }
  const int dB = tid & 127;
  f32x4 acc[4][4] = {};

  for (int e0k = 0; e0k < TE; e0k += 32) {
#pragma unroll
    for (int s = 0; s < 2; ++s) {
      int c = tid + 256 * s;
      int rc = c >> 2, cc = c & 3;
      uint4 va = *(const uint4*)(Pb + (size_t)(t0 + rc) * 4096 + e0k + cc * 8);
      *(uint4*)&AU[c * 4] = va;
    }
#pragma unroll
    for (int s = 0; s < 4; ++s) {
      int eg = (tid >> 7) + 2 * s;
      const float* src = V + (size_t)(e0k + eg * 4) * DD + d0 + dB;
      float x0 = src[0], x1 = src[DD], x2 = src[2 * DD], x3 = src[3 * DD];
      uint32_t r0 = rne_bf16(x0), r1 = rne_bf16(x1);
      uint32_t r2 = rne_bf16(x2), r3 = rne_bf16(x3);
      *(uint2*)&BtU[dB * 20 + eg * 2] =
          make_uint2(r0 | (r1 << 16), r2 | (r3 << 16));
    }
    __syncthreads();

    bf16x8 af[4];
#pragma unroll
    for (int mi = 0; mi < 4; ++mi) af[mi] = *(const bf16x8*)&AU[aoff[mi]];
#pragma unroll
    for (int ni = 0; ni < 4; ++ni) {
      bf16x8 bfr = *(const bf16x8*)&BtU[boff[ni]];
#pragma unroll
      for (int mi = 0; mi < 4; ++mi)
        acc[mi][ni] =
            __builtin_amdgcn_mfma_f32_16x16x32_bf16(af[mi], bfr, acc[mi][ni], 0, 0, 0);
    }
    __syncthreads();
  }

  float* outb = out + (size_t)b * TD * 2048 + 1024;
  const int tb = t0 + wm * 64 + q * 4;
  const int db = d0 + wn * 64 + lr;
#pragma unroll
  for (int mi = 0; mi < 4; ++mi)
#pragma unroll
    for (int ni = 0; ni < 4; ++ni)
#pragma unroll
      for (int i = 0; i < 4; ++i)
        outb[(size_t)(tb + mi * 16 + i) * 2048 + (db + ni * 16)] = acc[mi][ni][i];
}

__global__ __launch_bounds__(256)
void k4_copydec(const float4* __restrict__ dec4, float4* __restrict__ out4) {
  size_t g = (size_t)blockIdx.x * 512 + threadIdx.x;
#pragma unroll
  for (int s = 0; s < 2; ++s, g += 256) {
    size_t row = g >> 8, col = g & 255;
    out4[row * 512 + col] = dec4[g];
  }
}

extern "C" void kernel_launch(void* const* d_in, const int* in_sizes, int n_in,
                              void* d_out, int out_size, void* d_ws, size_t ws_size,
                              hipStream_t stream) {
  // setup_inputs order: [0]=encoder_outputs, [1]=decoder_outputs (fp32)
  const float* enc = (const float*)d_in[0];
  const float* dec = (const float*)d_in[1];
  float* out = (float*)d_out;

  const size_t M32 = 32ull << 20;  // 32 MiB per bf16 tensor
  bool fast = (d_ws != nullptr) && (ws_size >= 5 * M32);
  if (fast) {
    hipError_t e1 = hipFuncSetAttribute(
        (const void*)k_gemm256<3>, hipFuncAttributeMaxDynamicSharedMemorySize,
        131072);
    hipError_t e2 = hipFuncSetAttribute(
        (const void*)k_gemm256<1>, hipFuncAttributeMaxDynamicSharedMemorySize,
        131072);
    if (e1 != hipSuccess || e2 != hipSuccess) fast = false;
  }

  if (fast) {
    char* ws = (char*)d_ws;
    uint16_t* dhi = (uint16_t*)(ws);
    uint16_t* dlo = (uint16_t*)(ws + M32);
    uint16_t* ehi = (uint16_t*)(ws + 2 * M32);
    uint16_t* elo = (uint16_t*)(ws + 3 * M32);
    uint16_t* eT = (uint16_t*)(ws + 4 * M32);
    uint16_t* P = dhi;  // dec_hi region dead after K1; reuse for P

    hipLaunchKernelGGL(p0a_split_dec, dim3(2048), dim3(256), 0, stream,
                       (const float4*)dec, (uint32_t*)dhi, (uint32_t*)dlo);
    hipLaunchKernelGGL(p0b_split_enc, dim3(256, 1, 16), dim3(256), 0, stream,
                       enc, (uint32_t*)ehi, (uint32_t*)elo, eT);
    // S = Ah*Bh + Ah*Bl + Al*Bh  (K' = 3072 via segment pointers)
    hipLaunchKernelGGL(k_gemm256<3>, dim3(256), dim3(512), 131072, stream,
                       dhi, dhi, dlo, ehi, elo, ehi, out);
    hipLaunchKernelGGL(k2_softmax_v2, dim3(4096), dim3(256), 0, stream, dec, out, P);
    // ctx = P @ encT  (K' = 1024)
    hipLaunchKernelGGL(k_gemm256<1>, dim3(256), dim3(512), 131072, stream,
                       P, P, P, eT, eT, eT, out);
  } else {
    hipLaunchKernelGGL(k1_scores, dim3(8, 8, 16), dim3(256), 0, stream, dec, enc, out);
    hipLaunchKernelGGL(k2_softmax, dim3(4096), dim3(256), 0, stream, out);
    hipLaunchKernelGGL(k3_av, dim3(8, 8, 16), dim3(256), 0, stream, enc, out);
    hipLaunchKernelGGL(k4_copydec, dim3(8192), dim3(256), 0, stream,
                       (const float4*)dec, (float4*)out);
  }
}

// Round 3
// 410.926 us; speedup vs baseline: 1.1266x; 1.0123x over previous
//
#include <hip/hip_runtime.h>
#include <hip/hip_bf16.h>
#include <stdint.h>

typedef __bf16 bf16x8 __attribute__((ext_vector_type(8)));
typedef float f32x4 __attribute__((ext_vector_type(4)));

#define B_DIM 16
#define TD 1024
#define TE 1024
#define DD 1024

typedef __attribute__((address_space(1))) void as1_void;
typedef __attribute__((address_space(3))) void as3_void;

// global -> LDS direct copy, 16B per lane. LDS dest must be linear in lane order.
#define GLL16(gp, lp) \
  __builtin_amdgcn_global_load_lds((as1_void*)(gp), (as3_void*)(lp), 16, 0, 0)

#define SB __builtin_amdgcn_sched_barrier(0)
#define BAR()                      \
  do {                             \
    SB;                            \
    __builtin_amdgcn_s_barrier();  \
    SB;                            \
  } while (0)
#define VMW4()                                       \
  do {                                               \
    asm volatile("s_waitcnt vmcnt(4)" ::: "memory"); \
    SB;                                              \
  } while (0)

__device__ __forceinline__ uint32_t rne_bf16(float x) {
  uint32_t u = __builtin_bit_cast(uint32_t, x);
  return (u + 0x7FFFu + ((u >> 16) & 1u)) >> 16;
}

// RNE two-term split: x ~= hi + lo, both bf16.
__device__ __forceinline__ void split2(float x, uint32_t& hi, uint32_t& lo) {
  uint32_t h = rne_bf16(x);
  float hf = __builtin_bit_cast(float, h << 16);
  hi = h;
  lo = rne_bf16(x - hf);
}

// ---------------------------------------------------------------------------
// P0a: dec fp32 -> dec_hi, dec_lo bf16 (each element split exactly once).
// ---------------------------------------------------------------------------
__global__ __launch_bounds__(256)
void p0a_split_dec(const float4* __restrict__ dec4, uint32_t* __restrict__ dhi,
                   uint32_t* __restrict__ dlo) {
  size_t g = (size_t)blockIdx.x * 256 + threadIdx.x;
#pragma unroll
  for (int s = 0; s < 8; ++s, g += 524288) {
    float4 v = dec4[g];
    uint32_t h0, l0, h1, l1, h2, l2, h3, l3;
    split2(v.x, h0, l0);
    split2(v.y, h1, l1);
    split2(v.z, h2, l2);
    split2(v.w, h3, l3);
    *(uint2*)&dhi[g * 2] = make_uint2(h0 | (h1 << 16), h2 | (h3 << 16));
    *(uint2*)&dlo[g * 2] = make_uint2(l0 | (l1 << 16), l2 | (l3 << 16));
  }
}

// ---------------------------------------------------------------------------
// P0b: enc fp32 -> enc_hi, enc_lo bf16 [b][e][d], plus encT bf16 [b][d][e].
// ---------------------------------------------------------------------------
__global__ __launch_bounds__(256)
void p0b_split_enc(const float* __restrict__ enc, uint32_t* __restrict__ ehi,
                   uint32_t* __restrict__ elo, uint16_t* __restrict__ eT) {
  __shared__ uint16_t TT[64][65];
  const int tid = threadIdx.x;
  const int b = blockIdx.z;
  const int d0 = (blockIdx.x & 15) * 64, e0 = (blockIdx.x >> 4) * 64;
  const float* src = enc + (size_t)b * TE * DD;
#pragma unroll
  for (int s = 0; s < 4; ++s) {
    int c = tid + 256 * s;
    int row = c >> 4, c4 = c & 15;
    float4 v = *(const float4*)(src + (size_t)(e0 + row) * DD + d0 + c4 * 4);
    uint32_t h0, l0, h1, l1, h2, l2, h3, l3;
    split2(v.x, h0, l0);
    split2(v.y, h1, l1);
    split2(v.z, h2, l2);
    split2(v.w, h3, l3);
    size_t o = (((size_t)b * TE + e0 + row) * DD + d0 + c4 * 4) >> 1;
    *(uint2*)&ehi[o] = make_uint2(h0 | (h1 << 16), h2 | (h3 << 16));
    *(uint2*)&elo[o] = make_uint2(l0 | (l1 << 16), l2 | (l3 << 16));
    TT[row][c4 * 4 + 0] = (uint16_t)h0;
    TT[row][c4 * 4 + 1] = (uint16_t)h1;
    TT[row][c4 * 4 + 2] = (uint16_t)h2;
    TT[row][c4 * 4 + 3] = (uint16_t)h3;
  }
  __syncthreads();
#pragma unroll
  for (int s = 0; s < 4; ++s) {
    int c = tid + 256 * s;
    int d = c >> 4, e4 = c & 15;
    uint32_t w0 = (uint32_t)TT[e4 * 4 + 0][d] | ((uint32_t)TT[e4 * 4 + 1][d] << 16);
    uint32_t w1 = (uint32_t)TT[e4 * 4 + 2][d] | ((uint32_t)TT[e4 * 4 + 3][d] << 16);
    *(uint2*)&eT[((size_t)b * DD + d0 + d) * TE + e0 + e4 * 4] = make_uint2(w0, w1);
  }
}

// ---------------------------------------------------------------------------
// 256x256-tile 8-phase bf16 GEMM (HK-style schedule, plain HIP).
//   C[m][n] = sum_seg sum_k A_seg[m][k] * B_seg[n][k],  K'=NSEG*1024
// Geometry: BK=64, 512 thr = 8 waves (2M x 4N), per-wave C = 128x64.
// LDS 128 KiB dynamic: [buf2][op2][half2][128 rows][128 B].
// Swizzle: byte col ^= (row&7)<<4 via pre-swizzled global source (linear
// global_load_lds dest) + re-applied on ds_read addresses. Conflicts = 0
// (verified R2).
// Deep-prefetch schedule (T4, 3-phase cover, vmcnt never below 4):
//   ph1 (kk0,np0): 10 ds_read ; stage B0(t+1)->nxt
//   ph2 (kk0,np1):  2 ds_read ; stage B1(t+1)->nxt
//   ph3 (kk1,np1): 10 ds_read
//   ph4 (kk1,np0):  2 ds_read ; stage A0,A1(t+2)->cur ; vmcnt(4)
// Steady-state wait proof: at t's vmcnt(4), outstanding = A01(t+1)[4,
// issued t-1 ph4] + B0(t+1)[2, t ph1] + B1(t+1)[2, t ph2] + A01(t+2)[4,
// t ph4] = 12 -> drain to 4 leaves only A01(t+2); everything tile t+1
// reads has landed, drained loads had >=2 phases of cover. cur-A is dead
// after ph3 (last LDA), so ph4's A-stage into cur is safe (post-barrier).
// ---------------------------------------------------------------------------
template <int NSEG>
__global__ __launch_bounds__(512, 2)
void k_gemm256(const uint16_t* __restrict__ a0, const uint16_t* __restrict__ a1,
               const uint16_t* __restrict__ a2, const uint16_t* __restrict__ b0,
               const uint16_t* __restrict__ b1, const uint16_t* __restrict__ b2,
               float* __restrict__ out) {
  extern __shared__ char lds[];
  const int tid = threadIdx.x;
  const int lane = tid & 63, wave = tid >> 6;
  const int wr = wave >> 2, wc = wave & 3;
  const int lr = lane & 15, q = lane >> 4;

  // XCD-bijective swizzle (256 blocks, 8 XCDs, 32 per chunk)
  const int id = blockIdx.x;
  const int swz = (id & 7) * 32 + (id >> 3);
  const int b = swz >> 4, mblk = (swz >> 2) & 3, nblk = swz & 3;
  const size_t bOff = (size_t)b << 20;
  const uint16_t* As0 = a0 + bOff;
  const uint16_t* As1 = a1 + bOff;
  const uint16_t* As2 = a2 + bOff;
  const uint16_t* Bs0 = b0 + bOff;
  const uint16_t* Bs1 = b1 + bOff;
  const uint16_t* Bs2 = b2 + bOff;
  const int mrow0 = mblk * 256, nrow0 = nblk * 256;
  constexpr int T = NSEG * 16;

  f32x4 acc[8][4] = {};
  bf16x8 a[8], bA[2], bB[2];

  // stage one half-tile (128 rows x 64 k) of op (0=A,1=B), K-tile tau, into buf
  auto STAGE = [&](int op, int half, int tau, int buf) {
    int seg, klt;
    if constexpr (NSEG == 3) {
      seg = tau >> 4;
      klt = tau & 15;
    } else {
      seg = 0;
      klt = tau;
    }
    // no pointer arrays (rule #20): cndmask selects only
    const uint16_t* base;
    if (op == 0)
      base = (seg == 0) ? As0 : ((seg == 1) ? As1 : As2);
    else
      base = (seg == 0) ? Bs0 : ((seg == 1) ? Bs1 : Bs2);
    base += (size_t)((op == 0 ? mrow0 : nrow0) + half * 128) * 1024 + klt * 64;
    char* dst = lds + (((buf * 2 + op) * 2 + half) << 14);
#pragma unroll
    for (int j = 0; j < 2; ++j) {
      int chunk = j * 512 + tid;
      int row = chunk >> 3;
      int k8 = ((chunk & 7) ^ (row & 7)) << 3;  // inverse-swizzled source k
      GLL16(base + (size_t)row * 1024 + k8, dst + chunk * 16);
    }
  };

  auto LDA = [&](int kk, int buf) {
    const char* src = lds + (((buf * 2 + 0) * 2 + wr) << 14);
#pragma unroll
    for (int mi = 0; mi < 8; ++mi) {
      int rl = mi * 16 + lr;
      int col = (kk * 64 + q * 16) ^ ((rl & 7) << 4);
      a[mi] = *(const bf16x8*)(src + rl * 128 + col);
    }
  };
  auto LDB = [&](int kk, int nbase, bf16x8* bb, int buf) {
    const char* src = lds + (((buf * 2 + 1) * 2 + (wc >> 1)) << 14);
#pragma unroll
    for (int u = 0; u < 2; ++u) {
      int rl = (wc & 1) * 64 + (nbase + u) * 16 + lr;
      int col = (kk * 64 + q * 16) ^ ((rl & 7) << 4);
      bb[u] = *(const bf16x8*)(src + rl * 128 + col);
    }
  };
  auto MFMAQ = [&](bf16x8* bb, int npair) {
#pragma unroll
    for (int u = 0; u < 2; ++u)
#pragma unroll
      for (int mi = 0; mi < 8; ++mi)
        acc[mi][npair * 2 + u] = __builtin_amdgcn_mfma_f32_16x16x32_bf16(
            a[mi], bb[u], acc[mi][npair * 2 + u], 0, 0, 0);
  };

  // prologue: tile0's 4 half-tiles (8 loads) + A0,A1(1) (4 loads);
  // vmcnt(4) drains exactly tile0; A01(1) stays in flight.
  STAGE(0, 0, 0, 0);
  STAGE(0, 1, 0, 0);
  STAGE(1, 0, 0, 0);
  STAGE(1, 1, 0, 0);
  STAGE(0, 0, 1, 1);
  STAGE(0, 1, 1, 1);
  VMW4();
  BAR();

  for (int t = 0; t < T; ++t) {
    const int cur = t & 1, nxt = cur ^ 1;
    const int t1 = (t + 1 < T) ? t + 1 : 0;
    const int t2 = (t + 2 < T) ? t + 2 : t + 2 - T;
    // ---- phase 1: quadrant (kk=0, npair=0)
    LDA(0, cur);
    LDB(0, 0, bA, cur);
    STAGE(1, 0, t1, nxt);
    BAR();
    __builtin_amdgcn_s_setprio(1);
    MFMAQ(bA, 0);
    __builtin_amdgcn_s_setprio(0);
    BAR();
    // ---- phase 2: (0, 1)
    LDB(0, 2, bB, cur);
    STAGE(1, 1, t1, nxt);
    BAR();
    __builtin_amdgcn_s_setprio(1);
    MFMAQ(bB, 1);
    __builtin_amdgcn_s_setprio(0);
    BAR();
    // ---- phase 3: (1, 1)
    LDA(1, cur);
    LDB(1, 2, bB, cur);
    BAR();
    __builtin_amdgcn_s_setprio(1);
    MFMAQ(bB, 1);
    __builtin_amdgcn_s_setprio(0);
    BAR();
    // ---- phase 4: (1, 0); cur-A dead after ph3 -> stage A01(t+2) there
    LDB(1, 0, bA, cur);
    STAGE(0, 0, t2, cur);
    STAGE(0, 1, t2, cur);
    VMW4();
    BAR();
    __builtin_amdgcn_s_setprio(1);
    MFMAQ(bA, 0);
    __builtin_amdgcn_s_setprio(0);
    BAR();
  }

  // epilogue: C/D layout col = lane&15, row = (lane>>4)*4 + reg
  float* outp = out + (size_t)b * TD * 2048 + 1024;
  const int m0 = mrow0 + wr * 128 + q * 4;
  const int n0 = nrow0 + wc * 64 + lr;
#pragma unroll
  for (int mi = 0; mi < 8; ++mi)
#pragma unroll
    for (int ni = 0; ni < 4; ++ni)
#pragma unroll
      for (int i = 0; i < 4; ++i)
        outp[(size_t)(m0 + mi * 16 + i) * 2048 + (n0 + ni * 16)] = acc[mi][ni][i];
}

// ---------------------------------------------------------------------------
// K2 v2: softmax over e per (b,t) row; P (bf16) -> workspace; also copies the
// decoder row into out[b,t,0:1024].
// ---------------------------------------------------------------------------
__global__ __launch_bounds__(256)
void k2_softmax_v2(const float* __restrict__ dec, float* __restrict__ out,
                   uint16_t* __restrict__ P) {
  const int lane = threadIdx.x & 63;
  const int row = blockIdx.x * 4 + (threadIdx.x >> 6);
  const float* Srow = out + (size_t)row * 2048 + 1024;
  float4 v[4];
#pragma unroll
  for (int s = 0; s < 4; ++s) v[s] = *(const float4*)(Srow + lane * 4 + s * 256);
  float m = -1e30f;
#pragma unroll
  for (int s = 0; s < 4; ++s)
    m = fmaxf(m, fmaxf(fmaxf(v[s].x, v[s].y), fmaxf(v[s].z, v[s].w)));
#pragma unroll
  for (int o = 32; o > 0; o >>= 1) m = fmaxf(m, __shfl_xor(m, o));
  float e[16];
  float sum = 0.f;
#pragma unroll
  for (int s = 0; s < 4; ++s) {
    e[4 * s + 0] = __expf(v[s].x - m);
    e[4 * s + 1] = __expf(v[s].y - m);
    e[4 * s + 2] = __expf(v[s].z - m);
    e[4 * s + 3] = __expf(v[s].w - m);
    sum += e[4 * s + 0] + e[4 * s + 1] + e[4 * s + 2] + e[4 * s + 3];
  }
#pragma unroll
  for (int o = 32; o > 0; o >>= 1) sum += __shfl_xor(sum, o);
  const float inv = 1.0f / sum;
  uint32_t* Prow = (uint32_t*)(P + (size_t)row * 1024);
#pragma unroll
  for (int s = 0; s < 4; ++s) {
    uint32_t r0 = rne_bf16(e[4 * s + 0] * inv);
    uint32_t r1 = rne_bf16(e[4 * s + 1] * inv);
    uint32_t r2 = rne_bf16(e[4 * s + 2] * inv);
    uint32_t r3 = rne_bf16(e[4 * s + 3] * inv);
    *(uint2*)&Prow[lane * 2 + s * 128] =
        make_uint2(r0 | (r1 << 16), r2 | (r3 << 16));
  }
  const float4* d4 = (const float4*)(dec + (size_t)row * 1024);
  float4* o4 = (float4*)(out + (size_t)row * 2048);
#pragma unroll
  for (int s = 0; s < 4; ++s) o4[lane + s * 64] = d4[lane + s * 64];
}

// ===========================================================================
// FALLBACK PATH (verified pipeline) — used if workspace/LDS attr unavailable.
// ===========================================================================
__global__ __launch_bounds__(256, 2)
void k1_scores(const float* __restrict__ dec, const float* __restrict__ enc,
               float* __restrict__ out) {
  __shared__ uint32_t AhU[2048], AlU[2048], BhU[2048], BlU[2048];
  const int tid = threadIdx.x;
  const int lane = tid & 63;
  const int wave = tid >> 6;
  const int wm = wave >> 1, wn = wave & 1;
  const int b = blockIdx.z;
  const int t0 = blockIdx.y * 128, e0 = blockIdx.x * 128;
  const float* A = dec + (size_t)b * TD * DD;
  const float* Bm = enc + (size_t)b * TE * DD;

  const int r = tid >> 3, c4 = tid & 7;
  const float* aptr = A + (size_t)(t0 + r) * DD + c4 * 4;
  const float* bptr = Bm + (size_t)(e0 + r) * DD + c4 * 4;

  const int lr = lane & 15, q = lane >> 4;
  int aoff[4], boff[4];
#pragma unroll
  for (int i = 0; i < 4; ++i) {
    aoff[i] = (wm * 64 + i * 16 + lr) * 16 + q * 4;
    boff[i] = (wn * 64 + i * 16 + lr) * 16 + q * 4;
  }

  f32x4 acc[4][4] = {};

  for (int k0 = 0; k0 < DD; k0 += 32) {
#pragma unroll
    for (int s = 0; s < 4; ++s) {
      const float4 va = *(const float4*)(aptr + (size_t)(32 * s) * DD);
      const float4 vb = *(const float4*)(bptr + (size_t)(32 * s) * DD);
      const int woff = (r + 32 * s) * 16 + c4 * 2;
      {
        uint32_t u0 = __builtin_bit_cast(uint32_t, va.x);
        uint32_t u1 = __builtin_bit_cast(uint32_t, va.y);
        uint32_t u2 = __builtin_bit_cast(uint32_t, va.z);
        uint32_t u3 = __builtin_bit_cast(uint32_t, va.w);
        uint32_t m0 = u0 & 0xFFFF0000u, m1 = u1 & 0xFFFF0000u;
        uint32_t m2 = u2 & 0xFFFF0000u, m3 = u3 & 0xFFFF0000u;
        float l0 = va.x - __builtin_bit_cast(float, m0);
        float l1 = va.y - __builtin_bit_cast(float, m1);
        float l2 = va.z - __builtin_bit_cast(float, m2);
        float l3 = va.w - __builtin_bit_cast(float, m3);
        *(uint2*)&AhU[woff] = make_uint2((m0 >> 16) | m1, (m2 >> 16) | m3);
        *(uint2*)&AlU[woff] = make_uint2(
            (__builtin_bit_cast(uint32_t, l0) >> 16) |
                (__builtin_bit_cast(uint32_t, l1) & 0xFFFF0000u),
            (__builtin_bit_cast(uint32_t, l2) >> 16) |
                (__builtin_bit_cast(uint32_t, l3) & 0xFFFF0000u));
      }
      {
        uint32_t u0 = __builtin_bit_cast(uint32_t, vb.x);
        uint32_t u1 = __builtin_bit_cast(uint32_t, vb.y);
        uint32_t u2 = __builtin_bit_cast(uint32_t, vb.z);
        uint32_t u3 = __builtin_bit_cast(uint32_t, vb.w);
        uint32_t m0 = u0 & 0xFFFF0000u, m1 = u1 & 0xFFFF0000u;
        uint32_t m2 = u2 & 0xFFFF0000u, m3 = u3 & 0xFFFF0000u;
        float l0 = vb.x - __builtin_bit_cast(float, m0);
        float l1 = vb.y - __builtin_bit_cast(float, m1);
        float l2 = vb.z - __builtin_bit_cast(float, m2);
        float l3 = vb.w - __builtin_bit_cast(float, m3);
        *(uint2*)&BhU[woff] = make_uint2((m0 >> 16) | m1, (m2 >> 16) | m3);
        *(uint2*)&BlU[woff] = make_uint2(
            (__builtin_bit_cast(uint32_t, l0) >> 16) |
                (__builtin_bit_cast(uint32_t, l1) & 0xFFFF0000u),
            (__builtin_bit_cast(uint32_t, l2) >> 16) |
                (__builtin_bit_cast(uint32_t, l3) & 0xFFFF0000u));
      }
    }
    __syncthreads();

    bf16x8 ah[4], al[4];
#pragma unroll
    for (int mi = 0; mi < 4; ++mi) {
      ah[mi] = *(const bf16x8*)&AhU[aoff[mi]];
      al[mi] = *(const bf16x8*)&AlU[aoff[mi]];
    }
#pragma unroll
    for (int ni = 0; ni < 4; ++ni) {
      bf16x8 bh = *(const bf16x8*)&BhU[boff[ni]];
      bf16x8 bl = *(const bf16x8*)&BlU[boff[ni]];
#pragma unroll
      for (int mi = 0; mi < 4; ++mi) {
        f32x4 c = acc[mi][ni];
        c = __builtin_amdgcn_mfma_f32_16x16x32_bf16(al[mi], bh, c, 0, 0, 0);
        c = __builtin_amdgcn_mfma_f32_16x16x32_bf16(ah[mi], bl, c, 0, 0, 0);
        c = __builtin_amdgcn_mfma_f32_16x16x32_bf16(ah[mi], bh, c, 0, 0, 0);
        acc[mi][ni] = c;
      }
    }
    __syncthreads();
    aptr += 32;
    bptr += 32;
  }

  float* outb = out + (size_t)b * TD * 2048 + 1024;
  const int tb = t0 + wm * 64 + q * 4;
  const int eb = e0 + wn * 64 + lr;
#pragma unroll
  for (int mi = 0; mi < 4; ++mi)
#pragma unroll
    for (int ni = 0; ni < 4; ++ni)
#pragma unroll
      for (int i = 0; i < 4; ++i)
        outb[(size_t)(tb + mi * 16 + i) * 2048 + (eb + ni * 16)] = acc[mi][ni][i];
}

__global__ __launch_bounds__(256)
void k2_softmax(float* out) {
  const int lane = threadIdx.x & 63;
  const int row = blockIdx.x * 4 + (threadIdx.x >> 6);
  float* Srow = out + (size_t)row * 2048 + 1024;
  float4 v[4];
#pragma unroll
  for (int s = 0; s < 4; ++s) v[s] = *(const float4*)(Srow + lane * 4 + s * 256);
  float m = -1e30f;
#pragma unroll
  for (int s = 0; s < 4; ++s)
    m = fmaxf(m, fmaxf(fmaxf(v[s].x, v[s].y), fmaxf(v[s].z, v[s].w)));
#pragma unroll
  for (int o = 32; o > 0; o >>= 1) m = fmaxf(m, __shfl_xor(m, o));
  float e[16];
  float sum = 0.f;
#pragma unroll
  for (int s = 0; s < 4; ++s) {
    e[4 * s + 0] = __expf(v[s].x - m);
    e[4 * s + 1] = __expf(v[s].y - m);
    e[4 * s + 2] = __expf(v[s].z - m);
    e[4 * s + 3] = __expf(v[s].w - m);
    sum += e[4 * s + 0] + e[4 * s + 1] + e[4 * s + 2] + e[4 * s + 3];
  }
#pragma unroll
  for (int o = 32; o > 0; o >>= 1) sum += __shfl_xor(sum, o);
  const float inv = 1.0f / sum;
  uint32_t* Prow = (uint32_t*)(out + (size_t)row * 2048);
#pragma unroll
  for (int s = 0; s < 4; ++s) {
    uint32_t r0 = rne_bf16(e[4 * s + 0] * inv);
    uint32_t r1 = rne_bf16(e[4 * s + 1] * inv);
    uint32_t r2 = rne_bf16(e[4 * s + 2] * inv);
    uint32_t r3 = rne_bf16(e[4 * s + 3] * inv);
    *(uint2*)&Prow[lane * 2 + s * 128] =
        make_uint2(r0 | (r1 << 16), r2 | (r3 << 16));
  }
}

__global__ __launch_bounds__(256, 2)
void k3_av(const float* __restrict__ enc, float* __restrict__ out) {
  __shared__ uint32_t AU[2048];
  __shared__ uint32_t BtU[128 * 20];
  const int tid = threadIdx.x;
  const int lane = tid & 63, wave = tid >> 6;
  const int wm = wave >> 1, wn = wave & 1;
  const int b = blockIdx.z;
  const int t0 = blockIdx.y * 128, d0 = blockIdx.x * 128;
  const float* V = enc + (size_t)b * TE * DD;
  const uint16_t* Pb = (const uint16_t*)(out + (size_t)b * TD * 2048);
  const int lr = lane & 15, q = lane >> 4;
  int aoff[4], boff[4];
#pragma unroll
  for (int i = 0; i < 4; ++i) {
    aoff[i] = (wm * 64 + i * 16 + lr) * 16 + q * 4;
    boff[i] = (wn * 64 + i * 16 + lr) * 20 + q * 4;
  }
  const int dB = tid & 127;
  f32x4 acc[4][4] = {};

  for (int e0k = 0; e0k < TE; e0k += 32) {
#pragma unroll
    for (int s = 0; s < 2; ++s) {
      int c = tid + 256 * s;
      int rc = c >> 2, cc = c & 3;
      uint4 va = *(const uint4*)(Pb + (size_t)(t0 + rc) * 4096 + e0k + cc * 8);
      *(uint4*)&AU[c * 4] = va;
    }
#pragma unroll
    for (int s = 0; s < 4; ++s) {
      int eg = (tid >> 7) + 2 * s;
      const float* src = V + (size_t)(e0k + eg * 4) * DD + d0 + dB;
      float x0 = src[0], x1 = src[DD], x2 = src[2 * DD], x3 = src[3 * DD];
      uint32_t r0 = rne_bf16(x0), r1 = rne_bf16(x1);
      uint32_t r2 = rne_bf16(x2), r3 = rne_bf16(x3);
      *(uint2*)&BtU[dB * 20 + eg * 2] =
          make_uint2(r0 | (r1 << 16), r2 | (r3 << 16));
    }
    __syncthreads();

    bf16x8 af[4];
#pragma unroll
    for (int mi = 0; mi < 4; ++mi) af[mi] = *(const bf16x8*)&AU[aoff[mi]];
#pragma unroll
    for (int ni = 0; ni < 4; ++ni) {
      bf16x8 bfr = *(const bf16x8*)&BtU[boff[ni]];
#pragma unroll
      for (int mi = 0; mi < 4; ++mi)
        acc[mi][ni] =
            __builtin_amdgcn_mfma_f32_16x16x32_bf16(af[mi], bfr, acc[mi][ni], 0, 0, 0);
    }
    __syncthreads();
  }

  float* outb = out + (size_t)b * TD * 2048 + 1024;
  const int tb = t0 + wm * 64 + q * 4;
  const int db = d0 + wn * 64 + lr;
#pragma unroll
  for (int mi = 0; mi < 4; ++mi)
#pragma unroll
    for (int ni = 0; ni < 4; ++ni)
#pragma unroll
      for (int i = 0; i < 4; ++i)
        outb[(size_t)(tb + mi * 16 + i) * 2048 + (db + ni * 16)] = acc[mi][ni][i];
}

__global__ __launch_bounds__(256)
void k4_copydec(const float4* __restrict__ dec4, float4* __restrict__ out4) {
  size_t g = (size_t)blockIdx.x * 512 + threadIdx.x;
#pragma unroll
  for (int s = 0; s < 2; ++s, g += 256) {
    size_t row = g >> 8, col = g & 255;
    out4[row * 512 + col] = dec4[g];
  }
}

extern "C" void kernel_launch(void* const* d_in, const int* in_sizes, int n_in,
                              void* d_out, int out_size, void* d_ws, size_t ws_size,
                              hipStream_t stream) {
  // setup_inputs order: [0]=encoder_outputs, [1]=decoder_outputs (fp32)
  const float* enc = (const float*)d_in[0];
  const float* dec = (const float*)d_in[1];
  float* out = (float*)d_out;

  const size_t M32 = 32ull << 20;  // 32 MiB per bf16 tensor
  bool fast = (d_ws != nullptr) && (ws_size >= 5 * M32);
  if (fast) {
    hipError_t e1 = hipFuncSetAttribute(
        (const void*)k_gemm256<3>, hipFuncAttributeMaxDynamicSharedMemorySize,
        131072);
    hipError_t e2 = hipFuncSetAttribute(
        (const void*)k_gemm256<1>, hipFuncAttributeMaxDynamicSharedMemorySize,
        131072);
    if (e1 != hipSuccess || e2 != hipSuccess) fast = false;
  }

  if (fast) {
    char* ws = (char*)d_ws;
    uint16_t* dhi = (uint16_t*)(ws);
    uint16_t* dlo = (uint16_t*)(ws + M32);
    uint16_t* ehi = (uint16_t*)(ws + 2 * M32);
    uint16_t* elo = (uint16_t*)(ws + 3 * M32);
    uint16_t* eT = (uint16_t*)(ws + 4 * M32);
    uint16_t* P = dhi;  // dec_hi region dead after K1; reuse for P

    hipLaunchKernelGGL(p0a_split_dec, dim3(2048), dim3(256), 0, stream,
                       (const float4*)dec, (uint32_t*)dhi, (uint32_t*)dlo);
    hipLaunchKernelGGL(p0b_split_enc, dim3(256, 1, 16), dim3(256), 0, stream,
                       enc, (uint32_t*)ehi, (uint32_t*)elo, eT);
    // S = Ah*Bh + Ah*Bl + Al*Bh  (K' = 3072 via segment pointers)
    hipLaunchKernelGGL(k_gemm256<3>, dim3(256), dim3(512), 131072, stream,
                       dhi, dhi, dlo, ehi, elo, ehi, out);
    hipLaunchKernelGGL(k2_softmax_v2, dim3(4096), dim3(256), 0, stream, dec, out, P);
    // ctx = P @ encT  (K' = 1024)
    hipLaunchKernelGGL(k_gemm256<1>, dim3(256), dim3(512), 131072, stream,
                       P, P, P, eT, eT, eT, out);
  } else {
    hipLaunchKernelGGL(k1_scores, dim3(8, 8, 16), dim3(256), 0, stream, dec, enc, out);
    hipLaunchKernelGGL(k2_softmax, dim3(4096), dim3(256), 0, stream, out);
    hipLaunchKernelGGL(k3_av, dim3(8, 8, 16), dim3(256), 0, stream, enc, out);
    hipLaunchKernelGGL(k4_copydec, dim3(8192), dim3(256), 0, stream,
                       (const float4*)dec, (float4*)out);
  }
}

// Round 4
// 400.577 us; speedup vs baseline: 1.1557x; 1.0258x over previous
//
#include <hip/hip_runtime.h>
#include <hip/hip_bf16.h>
#include <stdint.h>

typedef __bf16 bf16x8 __attribute__((ext_vector_type(8)));
typedef float f32x4 __attribute__((ext_vector_type(4)));

#define B_DIM 16
#define TD 1024
#define TE 1024
#define DD 1024

typedef __attribute__((address_space(1))) void as1_void;
typedef __attribute__((address_space(3))) void as3_void;

// global -> LDS direct copy, 16B per lane. LDS dest must be linear in lane order.
#define GLL16(gp, lp) \
  __builtin_amdgcn_global_load_lds((as1_void*)(gp), (as3_void*)(lp), 16, 0, 0)

#define SB __builtin_amdgcn_sched_barrier(0)
#define BAR()                      \
  do {                             \
    SB;                            \
    __builtin_amdgcn_s_barrier();  \
    SB;                            \
  } while (0)
#define VMW4()                                       \
  do {                                               \
    asm volatile("s_waitcnt vmcnt(4)" ::: "memory"); \
    SB;                                              \
  } while (0)

__device__ __forceinline__ uint32_t rne_bf16(float x) {
  uint32_t u = __builtin_bit_cast(uint32_t, x);
  return (u + 0x7FFFu + ((u >> 16) & 1u)) >> 16;
}

// RNE two-term split: x ~= hi + lo, both bf16.
__device__ __forceinline__ void split2(float x, uint32_t& hi, uint32_t& lo) {
  uint32_t h = rne_bf16(x);
  float hf = __builtin_bit_cast(float, h << 16);
  hi = h;
  lo = rne_bf16(x - hf);
}

// ---------------------------------------------------------------------------
// P0a: dec fp32 -> dec_hi, dec_lo bf16 (split exactly once) + copy dec into
// out[b,t,0:1024] (moved here from k2; p0a reads dec anyway).
// ---------------------------------------------------------------------------
__global__ __launch_bounds__(256)
void p0a_split_dec(const float4* __restrict__ dec4, uint32_t* __restrict__ dhi,
                   uint32_t* __restrict__ dlo, float4* __restrict__ out4) {
  size_t g = (size_t)blockIdx.x * 256 + threadIdx.x;
#pragma unroll
  for (int s = 0; s < 8; ++s, g += 524288) {
    float4 v = dec4[g];
    uint32_t h0, l0, h1, l1, h2, l2, h3, l3;
    split2(v.x, h0, l0);
    split2(v.y, h1, l1);
    split2(v.z, h2, l2);
    split2(v.w, h3, l3);
    *(uint2*)&dhi[g * 2] = make_uint2(h0 | (h1 << 16), h2 | (h3 << 16));
    *(uint2*)&dlo[g * 2] = make_uint2(l0 | (l1 << 16), l2 | (l3 << 16));
    size_t row = g >> 8, col = g & 255;
    out4[row * 512 + col] = v;
  }
}

// ---------------------------------------------------------------------------
// P0b: enc fp32 -> enc_hi, enc_lo bf16 [b][e][d], plus encT bf16 [b][d][e].
// ---------------------------------------------------------------------------
__global__ __launch_bounds__(256)
void p0b_split_enc(const float* __restrict__ enc, uint32_t* __restrict__ ehi,
                   uint32_t* __restrict__ elo, uint16_t* __restrict__ eT) {
  __shared__ uint16_t TT[64][65];
  const int tid = threadIdx.x;
  const int b = blockIdx.z;
  const int d0 = (blockIdx.x & 15) * 64, e0 = (blockIdx.x >> 4) * 64;
  const float* src = enc + (size_t)b * TE * DD;
#pragma unroll
  for (int s = 0; s < 4; ++s) {
    int c = tid + 256 * s;
    int row = c >> 4, c4 = c & 15;
    float4 v = *(const float4*)(src + (size_t)(e0 + row) * DD + d0 + c4 * 4);
    uint32_t h0, l0, h1, l1, h2, l2, h3, l3;
    split2(v.x, h0, l0);
    split2(v.y, h1, l1);
    split2(v.z, h2, l2);
    split2(v.w, h3, l3);
    size_t o = (((size_t)b * TE + e0 + row) * DD + d0 + c4 * 4) >> 1;
    *(uint2*)&ehi[o] = make_uint2(h0 | (h1 << 16), h2 | (h3 << 16));
    *(uint2*)&elo[o] = make_uint2(l0 | (l1 << 16), l2 | (l3 << 16));
    TT[row][c4 * 4 + 0] = (uint16_t)h0;
    TT[row][c4 * 4 + 1] = (uint16_t)h1;
    TT[row][c4 * 4 + 2] = (uint16_t)h2;
    TT[row][c4 * 4 + 3] = (uint16_t)h3;
  }
  __syncthreads();
#pragma unroll
  for (int s = 0; s < 4; ++s) {
    int c = tid + 256 * s;
    int d = c >> 4, e4 = c & 15;
    uint32_t w0 = (uint32_t)TT[e4 * 4 + 0][d] | ((uint32_t)TT[e4 * 4 + 1][d] << 16);
    uint32_t w1 = (uint32_t)TT[e4 * 4 + 2][d] | ((uint32_t)TT[e4 * 4 + 3][d] << 16);
    *(uint2*)&eT[((size_t)b * DD + d0 + d) * TE + e0 + e4 * 4] = make_uint2(w0, w1);
  }
}

// ---------------------------------------------------------------------------
// 256x256-tile 8-phase bf16 GEMM, v3: zero-VALU hot loop.
//   C[m][n] = sum_seg sum_k A_seg[m][k]*B_seg[n][k],  K' = NSEG*1024.
// Geometry: BK=64, 512 thr = 8 waves (2M x 4N), per-wave C = 128x64.
// LDS 128 KiB dynamic: [buf2][op2][half2][128 rows][128 B], region = 16 KiB.
// Swizzle: byte col ^= (row&7)<<4 via pre-swizzled global src + on-read XOR.
// All ds_read addresses = 4 base VGPRs (A/B x kk0/kk1) + literal offsets
// (the XOR term depends only on lr&7, invariant across fragments); buffers
// alternate by +/-65536 pointer bump per tile. Stage src = uniform SGPR base
// (scalar seg/klt math) + loop-invariant lane offset -> saddr global_load_lds.
// Phases per K-tile t (reads {12,0,12,0}; stages {B0,B1,-,A0+A1}):
//   ph1: read a(kk0)x8, bA(kk0), bB(kk0); stage B.h0(t+1)->nxt; MFMA(bA,np0)
//   ph2: stage B.h1(t+1)->nxt;                                  MFMA(bB,np1)
//   ph3: read a(kk1)x8, bA(kk1), bB(kk1);                       MFMA(bB,np1)
//   ph4: stage A.h0+h1(t+2)->cur; vmcnt(4);                     MFMA(bA,np0)
// vmcnt proof (8 loads/tile): at ph4's wait, outstanding = A01(t+1)[4] +
// B0(t+1)[2] + B1(t+1)[2] + A01(t+2)[4] = 12 -> drain to 4 leaves only
// A01(t+2); all of tile t+1 has landed; never drains below 4. cur-A dead
// after ph3 (its reads complete before each wave's ph3 MFMA, barrier-sealed),
// so ph4's A-stage into cur is safe.
// ---------------------------------------------------------------------------
template <int NSEG>
__global__ __launch_bounds__(512, 2)
void k_gemm256(const uint16_t* __restrict__ a0, const uint16_t* __restrict__ a1,
               const uint16_t* __restrict__ a2, const uint16_t* __restrict__ b0,
               const uint16_t* __restrict__ b1, const uint16_t* __restrict__ b2,
               float* __restrict__ out) {
  extern __shared__ char lds[];
  const int tid = threadIdx.x;
  const int lane = tid & 63, wave = tid >> 6;
  const int wr = wave >> 2, wc = wave & 3;
  const int lr = lane & 15, q = lane >> 4;

  // XCD-bijective swizzle (256 blocks, 8 XCDs, 32 per chunk)
  const int id = blockIdx.x;
  const int swz = (id & 7) * 32 + (id >> 3);
  const int b = swz >> 4, mblk = (swz >> 2) & 3, nblk = swz & 3;
  const size_t bOff = (size_t)b << 20;
  const int mrow0 = mblk * 256, nrow0 = nblk * 256;
  constexpr int T = NSEG * 16;

  // ---- uniform staging bases (SGPR): seg bases with row offset folded in
  const uint16_t* aS0 = a0 + bOff + (size_t)mrow0 * 1024;
  const uint16_t* aS1 = a1 + bOff + (size_t)mrow0 * 1024;
  const uint16_t* aS2 = a2 + bOff + (size_t)mrow0 * 1024;
  const uint16_t* bS0 = b0 + bOff + (size_t)nrow0 * 1024;
  const uint16_t* bS1 = b1 + bOff + (size_t)nrow0 * 1024;
  const uint16_t* bS2 = b2 + bOff + (size_t)nrow0 * 1024;

  // ---- loop-invariant per-lane stage offset (elements)
  const int r8 = tid >> 3, c8 = tid & 7;
  const int laneOff = r8 * 1024 + ((c8 ^ (r8 & 7)) << 3);
  char* dTid = lds + tid * 16;

  // stage one half-tile of op at K-tile tau into REGION (0..7).
#define STAGE_OP(P0_, P1_, P2_, HALF_, TAU_, REGION_)                         \
  do {                                                                        \
    int sg_ = (NSEG == 3) ? ((TAU_) >> 4) : 0;                                \
    int kl_ = (TAU_) & 15;                                                    \
    const uint16_t* s_ =                                                      \
        ((NSEG == 3) ? (sg_ == 0 ? (P0_) : (sg_ == 1 ? (P1_) : (P2_)))        \
                     : (P0_)) +                                               \
        (size_t)(HALF_)*131072 + (kl_ << 6) + laneOff;                        \
    char* d_ = dTid + (REGION_)*16384;                                        \
    GLL16(s_, d_);                                                            \
    GLL16(s_ + 65536, d_ + 8192);                                             \
  } while (0)

  // ---- ds-read base pointers (buf0), literal offsets do the rest.
  const int xr = (lr & 7) << 4;
  const int colx = (q * 16) ^ xr;
  const char* aRd0 = lds + (wr << 14) + lr * 128 + colx;          // A kk0
  const char* aRd1 = lds + (wr << 14) + lr * 128 + (colx ^ 64);   // A kk1
  const char* bRdB = lds + ((2 + (wc >> 1)) << 14) + (wc & 1) * 8192 + lr * 128;
  const char* bRd0 = bRdB + colx;                                 // B kk0
  const char* bRd1 = bRdB + (colx ^ 64);                          // B kk1

  f32x4 acc[8][4] = {};
  bf16x8 a[8], bA[2], bB[2];

#define LDA_ALL(SRC_)                                    \
  do {                                                   \
    _Pragma("unroll") for (int mi = 0; mi < 8; ++mi)     \
        a[mi] = *(const bf16x8*)((SRC_) + mi * 2048);    \
  } while (0)
#define LDB2(SRC_, NB_, DST_)                               \
  do {                                                      \
    DST_[0] = *(const bf16x8*)((SRC_) + (NB_)*2048);        \
    DST_[1] = *(const bf16x8*)((SRC_) + ((NB_) + 1) * 2048);\
  } while (0)

  auto MFMAQ = [&](bf16x8* bb, int npair) {
#pragma unroll
    for (int u = 0; u < 2; ++u)
#pragma unroll
      for (int mi = 0; mi < 8; ++mi)
        acc[mi][npair * 2 + u] = __builtin_amdgcn_mfma_f32_16x16x32_bf16(
            a[mi], bb[u], acc[mi][npair * 2 + u], 0, 0, 0);
  };

  // prologue: tile0 (A0,A1,B0,B1 -> buf0) + A0,A1(t=1) -> buf1 (12 loads);
  // vmcnt(4) drains tile0 exactly, A01(1) stays in flight.
  STAGE_OP(aS0, aS1, aS2, 0, 0, 0);
  STAGE_OP(aS0, aS1, aS2, 1, 0, 1);
  STAGE_OP(bS0, bS1, bS2, 0, 0, 2);
  STAGE_OP(bS0, bS1, bS2, 1, 0, 3);
  STAGE_OP(aS0, aS1, aS2, 0, 1, 4);
  STAGE_OP(aS0, aS1, aS2, 1, 1, 5);
  VMW4();
  BAR();

  int dir = 65536;  // read-base toggle buf0 <-> buf1
#pragma unroll 1
  for (int t = 0; t < T; ++t) {
    const int cur = t & 1, nxt = cur ^ 1;
    const int t1 = (t + 1 < T) ? t + 1 : t + 1 - T;
    const int t2 = (t + 2 < T) ? t + 2 : t + 2 - T;
    // ---- ph1: 12 reads (kk0) ; stage B.h0(t+1)->nxt
    LDA_ALL(aRd0);
    LDB2(bRd0, 0, bA);
    LDB2(bRd0, 2, bB);
    STAGE_OP(bS0, bS1, bS2, 0, t1, nxt * 4 + 2);
    BAR();
    __builtin_amdgcn_s_setprio(1);
    MFMAQ(bA, 0);
    __builtin_amdgcn_s_setprio(0);
    BAR();
    // ---- ph2: stage B.h1(t+1)->nxt  (bB loaded ph1 -> no lgkm tail)
    STAGE_OP(bS0, bS1, bS2, 1, t1, nxt * 4 + 3);
    BAR();
    __builtin_amdgcn_s_setprio(1);
    MFMAQ(bB, 1);
    __builtin_amdgcn_s_setprio(0);
    BAR();
    // ---- ph3: 12 reads (kk1)
    LDA_ALL(aRd1);
    LDB2(bRd1, 0, bA);
    LDB2(bRd1, 2, bB);
    BAR();
    __builtin_amdgcn_s_setprio(1);
    MFMAQ(bB, 1);
    __builtin_amdgcn_s_setprio(0);
    BAR();
    // ---- ph4: stage A.h0+h1(t+2)->cur ; vmcnt(4)  (bA loaded ph3 -> no tail)
    STAGE_OP(aS0, aS1, aS2, 0, t2, cur * 4 + 0);
    STAGE_OP(aS0, aS1, aS2, 1, t2, cur * 4 + 1);
    VMW4();
    BAR();
    __builtin_amdgcn_s_setprio(1);
    MFMAQ(bA, 0);
    __builtin_amdgcn_s_setprio(0);
    BAR();
    // toggle read bases to the other buffer
    aRd0 += dir;
    aRd1 += dir;
    bRd0 += dir;
    bRd1 += dir;
    dir = -dir;
  }
#undef STAGE_OP
#undef LDA_ALL
#undef LDB2

  // epilogue: C/D layout col = lane&15, row = (lane>>4)*4 + reg
  float* outp = out + (size_t)b * TD * 2048 + 1024;
  const int m0 = mrow0 + wr * 128 + q * 4;
  const int n0 = nrow0 + wc * 64 + lr;
#pragma unroll
  for (int mi = 0; mi < 8; ++mi)
#pragma unroll
    for (int ni = 0; ni < 4; ++ni)
#pragma unroll
      for (int i = 0; i < 4; ++i)
        outp[(size_t)(m0 + mi * 16 + i) * 2048 + (n0 + ni * 16)] = acc[mi][ni][i];
}

// ---------------------------------------------------------------------------
// K2 v3: softmax over e per (b,t) row; P (bf16) -> workspace. (dec copy now
// lives in p0a.)
// ---------------------------------------------------------------------------
__global__ __launch_bounds__(256)
void k2_softmax_v3(const float* __restrict__ out, uint16_t* __restrict__ P) {
  const int lane = threadIdx.x & 63;
  const int row = blockIdx.x * 4 + (threadIdx.x >> 6);
  const float* Srow = out + (size_t)row * 2048 + 1024;
  float4 v[4];
#pragma unroll
  for (int s = 0; s < 4; ++s) v[s] = *(const float4*)(Srow + lane * 4 + s * 256);
  float m = -1e30f;
#pragma unroll
  for (int s = 0; s < 4; ++s)
    m = fmaxf(m, fmaxf(fmaxf(v[s].x, v[s].y), fmaxf(v[s].z, v[s].w)));
#pragma unroll
  for (int o = 32; o > 0; o >>= 1) m = fmaxf(m, __shfl_xor(m, o));
  float e[16];
  float sum = 0.f;
#pragma unroll
  for (int s = 0; s < 4; ++s) {
    e[4 * s + 0] = __expf(v[s].x - m);
    e[4 * s + 1] = __expf(v[s].y - m);
    e[4 * s + 2] = __expf(v[s].z - m);
    e[4 * s + 3] = __expf(v[s].w - m);
    sum += e[4 * s + 0] + e[4 * s + 1] + e[4 * s + 2] + e[4 * s + 3];
  }
#pragma unroll
  for (int o = 32; o > 0; o >>= 1) sum += __shfl_xor(sum, o);
  const float inv = 1.0f / sum;
  uint32_t* Prow = (uint32_t*)(P + (size_t)row * 1024);
#pragma unroll
  for (int s = 0; s < 4; ++s) {
    uint32_t r0 = rne_bf16(e[4 * s + 0] * inv);
    uint32_t r1 = rne_bf16(e[4 * s + 1] * inv);
    uint32_t r2 = rne_bf16(e[4 * s + 2] * inv);
    uint32_t r3 = rne_bf16(e[4 * s + 3] * inv);
    *(uint2*)&Prow[lane * 2 + s * 128] =
        make_uint2(r0 | (r1 << 16), r2 | (r3 << 16));
  }
}

// ===========================================================================
// FALLBACK PATH (verified pipeline) — used if workspace/LDS attr unavailable.
// ===========================================================================
__global__ __launch_bounds__(256, 2)
void k1_scores(const float* __restrict__ dec, const float* __restrict__ enc,
               float* __restrict__ out) {
  __shared__ uint32_t AhU[2048], AlU[2048], BhU[2048], BlU[2048];
  const int tid = threadIdx.x;
  const int lane = tid & 63;
  const int wave = tid >> 6;
  const int wm = wave >> 1, wn = wave & 1;
  const int b = blockIdx.z;
  const int t0 = blockIdx.y * 128, e0 = blockIdx.x * 128;
  const float* A = dec + (size_t)b * TD * DD;
  const float* Bm = enc + (size_t)b * TE * DD;

  const int r = tid >> 3, c4 = tid & 7;
  const float* aptr = A + (size_t)(t0 + r) * DD + c4 * 4;
  const float* bptr = Bm + (size_t)(e0 + r) * DD + c4 * 4;

  const int lr = lane & 15, q = lane >> 4;
  int aoff[4], boff[4];
#pragma unroll
  for (int i = 0; i < 4; ++i) {
    aoff[i] = (wm * 64 + i * 16 + lr) * 16 + q * 4;
    boff[i] = (wn * 64 + i * 16 + lr) * 16 + q * 4;
  }

  f32x4 acc[4][4] = {};

  for (int k0 = 0; k0 < DD; k0 += 32) {
#pragma unroll
    for (int s = 0; s < 4; ++s) {
      const float4 va = *(const float4*)(aptr + (size_t)(32 * s) * DD);
      const float4 vb = *(const float4*)(bptr + (size_t)(32 * s) * DD);
      const int woff = (r + 32 * s) * 16 + c4 * 2;
      {
        uint32_t u0 = __builtin_bit_cast(uint32_t, va.x);
        uint32_t u1 = __builtin_bit_cast(uint32_t, va.y);
        uint32_t u2 = __builtin_bit_cast(uint32_t, va.z);
        uint32_t u3 = __builtin_bit_cast(uint32_t, va.w);
        uint32_t m0 = u0 & 0xFFFF0000u, m1 = u1 & 0xFFFF0000u;
        uint32_t m2 = u2 & 0xFFFF0000u, m3 = u3 & 0xFFFF0000u;
        float l0 = va.x - __builtin_bit_cast(float, m0);
        float l1 = va.y - __builtin_bit_cast(float, m1);
        float l2 = va.z - __builtin_bit_cast(float, m2);
        float l3 = va.w - __builtin_bit_cast(float, m3);
        *(uint2*)&AhU[woff] = make_uint2((m0 >> 16) | m1, (m2 >> 16) | m3);
        *(uint2*)&AlU[woff] = make_uint2(
            (__builtin_bit_cast(uint32_t, l0) >> 16) |
                (__builtin_bit_cast(uint32_t, l1) & 0xFFFF0000u),
            (__builtin_bit_cast(uint32_t, l2) >> 16) |
                (__builtin_bit_cast(uint32_t, l3) & 0xFFFF0000u));
      }
      {
        uint32_t u0 = __builtin_bit_cast(uint32_t, vb.x);
        uint32_t u1 = __builtin_bit_cast(uint32_t, vb.y);
        uint32_t u2 = __builtin_bit_cast(uint32_t, vb.z);
        uint32_t u3 = __builtin_bit_cast(uint32_t, vb.w);
        uint32_t m0 = u0 & 0xFFFF0000u, m1 = u1 & 0xFFFF0000u;
        uint32_t m2 = u2 & 0xFFFF0000u, m3 = u3 & 0xFFFF0000u;
        float l0 = vb.x - __builtin_bit_cast(float, m0);
        float l1 = vb.y - __builtin_bit_cast(float, m1);
        float l2 = vb.z - __builtin_bit_cast(float, m2);
        float l3 = vb.w - __builtin_bit_cast(float, m3);
        *(uint2*)&BhU[woff] = make_uint2((m0 >> 16) | m1, (m2 >> 16) | m3);
        *(uint2*)&BlU[woff] = make_uint2(
            (__builtin_bit_cast(uint32_t, l0) >> 16) |
                (__builtin_bit_cast(uint32_t, l1) & 0xFFFF0000u),
            (__builtin_bit_cast(uint32_t, l2) >> 16) |
                (__builtin_bit_cast(uint32_t, l3) & 0xFFFF0000u));
      }
    }
    __syncthreads();

    bf16x8 ah[4], al[4];
#pragma unroll
    for (int mi = 0; mi < 4; ++mi) {
      ah[mi] = *(const bf16x8*)&AhU[aoff[mi]];
      al[mi] = *(const bf16x8*)&AlU[aoff[mi]];
    }
#pragma unroll
    for (int ni = 0; ni < 4; ++ni) {
      bf16x8 bh = *(const bf16x8*)&BhU[boff[ni]];
      bf16x8 bl = *(const bf16x8*)&BlU[boff[ni]];
#pragma unroll
      for (int mi = 0; mi < 4; ++mi) {
        f32x4 c = acc[mi][ni];
        c = __builtin_amdgcn_mfma_f32_16x16x32_bf16(al[mi], bh, c, 0, 0, 0);
        c = __builtin_amdgcn_mfma_f32_16x16x32_bf16(ah[mi], bl, c, 0, 0, 0);
        c = __builtin_amdgcn_mfma_f32_16x16x32_bf16(ah[mi], bh, c, 0, 0, 0);
        acc[mi][ni] = c;
      }
    }
    __syncthreads();
    aptr += 32;
    bptr += 32;
  }

  float* outb = out + (size_t)b * TD * 2048 + 1024;
  const int tb = t0 + wm * 64 + q * 4;
  const int eb = e0 + wn * 64 + lr;
#pragma unroll
  for (int mi = 0; mi < 4; ++mi)
#pragma unroll
    for (int ni = 0; ni < 4; ++ni)
#pragma unroll
      for (int i = 0; i < 4; ++i)
        outb[(size_t)(tb + mi * 16 + i) * 2048 + (eb + ni * 16)] = acc[mi][ni][i];
}

__global__ __launch_bounds__(256)
void k2_softmax(float* out) {
  const int lane = threadIdx.x & 63;
  const int row = blockIdx.x * 4 + (threadIdx.x >> 6);
  float* Srow = out + (size_t)row * 2048 + 1024;
  float4 v[4];
#pragma unroll
  for (int s = 0; s < 4; ++s) v[s] = *(const float4*)(Srow + lane * 4 + s * 256);
  float m = -1e30f;
#pragma unroll
  for (int s = 0; s < 4; ++s)
    m = fmaxf(m, fmaxf(fmaxf(v[s].x, v[s].y), fmaxf(v[s].z, v[s].w)));
#pragma unroll
  for (int o = 32; o > 0; o >>= 1) m = fmaxf(m, __shfl_xor(m, o));
  float e[16];
  float sum = 0.f;
#pragma unroll
  for (int s = 0; s < 4; ++s) {
    e[4 * s + 0] = __expf(v[s].x - m);
    e[4 * s + 1] = __expf(v[s].y - m);
    e[4 * s + 2] = __expf(v[s].z - m);
    e[4 * s + 3] = __expf(v[s].w - m);
    sum += e[4 * s + 0] + e[4 * s + 1] + e[4 * s + 2] + e[4 * s + 3];
  }
#pragma unroll
  for (int o = 32; o > 0; o >>= 1) sum += __shfl_xor(sum, o);
  const float inv = 1.0f / sum;
  uint32_t* Prow = (uint32_t*)(out + (size_t)row * 2048);
#pragma unroll
  for (int s = 0; s < 4; ++s) {
    uint32_t r0 = rne_bf16(e[4 * s + 0] * inv);
    uint32_t r1 = rne_bf16(e[4 * s + 1] * inv);
    uint32_t r2 = rne_bf16(e[4 * s + 2] * inv);
    uint32_t r3 = rne_bf16(e[4 * s + 3] * inv);
    *(uint2*)&Prow[lane * 2 + s * 128] =
        make_uint2(r0 | (r1 << 16), r2 | (r3 << 16));
  }
}

__global__ __launch_bounds__(256, 2)
void k3_av(const float* __restrict__ enc, float* __restrict__ out) {
  __shared__ uint32_t AU[2048];
  __shared__ uint32_t BtU[128 * 20];
  const int tid = threadIdx.x;
  const int lane = tid & 63, wave = tid >> 6;
  const int wm = wave >> 1, wn = wave & 1;
  const int b = blockIdx.z;
  const int t0 = blockIdx.y * 128, d0 = blockIdx.x * 128;
  const float* V = enc + (size_t)b * TE * DD;
  const uint16_t* Pb = (const uint16_t*)(out + (size_t)b * TD * 2048);
  const int lr = lane & 15, q = lane >> 4;
  int aoff[4], boff[4];
#pragma unroll
  for (int i = 0; i < 4; ++i) {
    aoff[i] = (wm * 64 + i * 16 + lr) * 16 + q * 4;
    boff[i] = (wn * 64 + i * 16 + lr) * 20 + q * 4;
  }
  const int dB = tid & 127;
  f32x4 acc[4][4] = {};

  for (int e0k = 0; e0k < TE; e0k += 32) {
#pragma unroll
    for (int s = 0; s < 2; ++s) {
      int c = tid + 256 * s;
      int rc = c >> 2, cc = c & 3;
      uint4 va = *(const uint4*)(Pb + (size_t)(t0 + rc) * 4096 + e0k + cc * 8);
      *(uint4*)&AU[c * 4] = va;
    }
#pragma unroll
    for (int s = 0; s < 4; ++s) {
      int eg = (tid >> 7) + 2 * s;
      const float* src = V + (size_t)(e0k + eg * 4) * DD + d0 + dB;
      float x0 = src[0], x1 = src[DD], x2 = src[2 * DD], x3 = src[3 * DD];
      uint32_t r0 = rne_bf16(x0), r1 = rne_bf16(x1);
      uint32_t r2 = rne_bf16(x2), r3 = rne_bf16(x3);
      *(uint2*)&BtU[dB * 20 + eg * 2] =
          make_uint2(r0 | (r1 << 16), r2 | (r3 << 16));
    }
    __syncthreads();

    bf16x8 af[4];
#pragma unroll
    for (int mi = 0; mi < 4; ++mi) af[mi] = *(const bf16x8*)&AU[aoff[mi]];
#pragma unroll
    for (int ni = 0; ni < 4; ++ni) {
      bf16x8 bfr = *(const bf16x8*)&BtU[boff[ni]];
#pragma unroll
      for (int mi = 0; mi < 4; ++mi)
        acc[mi][ni] =
            __builtin_amdgcn_mfma_f32_16x16x32_bf16(af[mi], bfr, acc[mi][ni], 0, 0, 0);
    }
    __syncthreads();
  }

  float* outb = out + (size_t)b * TD * 2048 + 1024;
  const int tb = t0 + wm * 64 + q * 4;
  const int db = d0 + wn * 64 + lr;
#pragma unroll
  for (int mi = 0; mi < 4; ++mi)
#pragma unroll
    for (int ni = 0; ni < 4; ++ni)
#pragma unroll
      for (int i = 0; i < 4; ++i)
        outb[(size_t)(tb + mi * 16 + i) * 2048 + (db + ni * 16)] = acc[mi][ni][i];
}

__global__ __launch_bounds__(256)
void k4_copydec(const float4* __restrict__ dec4, float4* __restrict__ out4) {
  size_t g = (size_t)blockIdx.x * 512 + threadIdx.x;
#pragma unroll
  for (int s = 0; s < 2; ++s, g += 256) {
    size_t row = g >> 8, col = g & 255;
    out4[row * 512 + col] = dec4[g];
  }
}

extern "C" void kernel_launch(void* const* d_in, const int* in_sizes, int n_in,
                              void* d_out, int out_size, void* d_ws, size_t ws_size,
                              hipStream_t stream) {
  // setup_inputs order: [0]=encoder_outputs, [1]=decoder_outputs (fp32)
  const float* enc = (const float*)d_in[0];
  const float* dec = (const float*)d_in[1];
  float* out = (float*)d_out;

  const size_t M32 = 32ull << 20;  // 32 MiB per bf16 tensor
  bool fast = (d_ws != nullptr) && (ws_size >= 5 * M32);
  if (fast) {
    hipError_t e1 = hipFuncSetAttribute(
        (const void*)k_gemm256<3>, hipFuncAttributeMaxDynamicSharedMemorySize,
        131072);
    hipError_t e2 = hipFuncSetAttribute(
        (const void*)k_gemm256<1>, hipFuncAttributeMaxDynamicSharedMemorySize,
        131072);
    if (e1 != hipSuccess || e2 != hipSuccess) fast = false;
  }

  if (fast) {
    char* ws = (char*)d_ws;
    uint16_t* dhi = (uint16_t*)(ws);
    uint16_t* dlo = (uint16_t*)(ws + M32);
    uint16_t* ehi = (uint16_t*)(ws + 2 * M32);
    uint16_t* elo = (uint16_t*)(ws + 3 * M32);
    uint16_t* eT = (uint16_t*)(ws + 4 * M32);
    uint16_t* P = dhi;  // dec_hi region dead after K1; reuse for P

    hipLaunchKernelGGL(p0a_split_dec, dim3(2048), dim3(256), 0, stream,
                       (const float4*)dec, (uint32_t*)dhi, (uint32_t*)dlo,
                       (float4*)out);
    hipLaunchKernelGGL(p0b_split_enc, dim3(256, 1, 16), dim3(256), 0, stream,
                       enc, (uint32_t*)ehi, (uint32_t*)elo, eT);
    // S = Ah*Bh + Ah*Bl + Al*Bh  (K' = 3072 via segment pointers)
    hipLaunchKernelGGL(k_gemm256<3>, dim3(256), dim3(512), 131072, stream,
                       dhi, dhi, dlo, ehi, elo, ehi, out);
    hipLaunchKernelGGL(k2_softmax_v3, dim3(4096), dim3(256), 0, stream, out, P);
    // ctx = P @ encT  (K' = 1024)
    hipLaunchKernelGGL(k_gemm256<1>, dim3(256), dim3(512), 131072, stream,
                       P, P, P, eT, eT, eT, out);
  } else {
    hipLaunchKernelGGL(k1_scores, dim3(8, 8, 16), dim3(256), 0, stream, dec, enc, out);
    hipLaunchKernelGGL(k2_softmax, dim3(4096), dim3(256), 0, stream, out);
    hipLaunchKernelGGL(k3_av, dim3(8, 8, 16), dim3(256), 0, stream, enc, out);
    hipLaunchKernelGGL(k4_copydec, dim3(8192), dim3(256), 0, stream,
                       (const float4*)dec, (float4*)out);
  }
}

// Round 5
// 394.107 us; speedup vs baseline: 1.1747x; 1.0164x over previous
//
#include <hip/hip_runtime.h>
#include <hip/hip_bf16.h>
#include <stdint.h>

typedef __bf16 bf16x8 __attribute__((ext_vector_type(8)));
typedef float f32x4 __attribute__((ext_vector_type(4)));

#define B_DIM 16
#define TD 1024
#define TE 1024
#define DD 1024

typedef __attribute__((address_space(1))) void as1_void;
typedef __attribute__((address_space(3))) void as3_void;

// global -> LDS direct copy, 16B per lane. LDS dest must be linear in lane order.
#define GLL16(gp, lp) \
  __builtin_amdgcn_global_load_lds((as1_void*)(gp), (as3_void*)(lp), 16, 0, 0)

#define SB __builtin_amdgcn_sched_barrier(0)
#define BAR()                      \
  do {                             \
    SB;                            \
    __builtin_amdgcn_s_barrier();  \
    SB;                            \
  } while (0)
#define VMW4()                                       \
  do {                                               \
    asm volatile("s_waitcnt vmcnt(4)" ::: "memory"); \
    SB;                                              \
  } while (0)

__device__ __forceinline__ uint32_t rne_bf16(float x) {
  uint32_t u = __builtin_bit_cast(uint32_t, x);
  return (u + 0x7FFFu + ((u >> 16) & 1u)) >> 16;
}

// RNE two-term split: x ~= hi + lo, both bf16.
__device__ __forceinline__ void split2(float x, uint32_t& hi, uint32_t& lo) {
  uint32_t h = rne_bf16(x);
  float hf = __builtin_bit_cast(float, h << 16);
  hi = h;
  lo = rne_bf16(x - hf);
}

// ---------------------------------------------------------------------------
// P0a: dec fp32 -> dec_hi, dec_lo bf16 (split exactly once) + copy dec into
// out[b,t,0:1024].
// ---------------------------------------------------------------------------
__global__ __launch_bounds__(256)
void p0a_split_dec(const float4* __restrict__ dec4, uint32_t* __restrict__ dhi,
                   uint32_t* __restrict__ dlo, float4* __restrict__ out4) {
  size_t g = (size_t)blockIdx.x * 256 + threadIdx.x;
#pragma unroll
  for (int s = 0; s < 8; ++s, g += 524288) {
    float4 v = dec4[g];
    uint32_t h0, l0, h1, l1, h2, l2, h3, l3;
    split2(v.x, h0, l0);
    split2(v.y, h1, l1);
    split2(v.z, h2, l2);
    split2(v.w, h3, l3);
    *(uint2*)&dhi[g * 2] = make_uint2(h0 | (h1 << 16), h2 | (h3 << 16));
    *(uint2*)&dlo[g * 2] = make_uint2(l0 | (l1 << 16), l2 | (l3 << 16));
    size_t row = g >> 8, col = g & 255;
    out4[row * 512 + col] = v;
  }
}

// ---------------------------------------------------------------------------
// P0b: enc fp32 -> enc_hi, enc_lo bf16 [b][e][d], plus encT bf16 [b][d][e].
// ---------------------------------------------------------------------------
__global__ __launch_bounds__(256)
void p0b_split_enc(const float* __restrict__ enc, uint32_t* __restrict__ ehi,
                   uint32_t* __restrict__ elo, uint16_t* __restrict__ eT) {
  __shared__ uint16_t TT[64][65];
  const int tid = threadIdx.x;
  const int b = blockIdx.z;
  const int d0 = (blockIdx.x & 15) * 64, e0 = (blockIdx.x >> 4) * 64;
  const float* src = enc + (size_t)b * TE * DD;
#pragma unroll
  for (int s = 0; s < 4; ++s) {
    int c = tid + 256 * s;
    int row = c >> 4, c4 = c & 15;
    float4 v = *(const float4*)(src + (size_t)(e0 + row) * DD + d0 + c4 * 4);
    uint32_t h0, l0, h1, l1, h2, l2, h3, l3;
    split2(v.x, h0, l0);
    split2(v.y, h1, l1);
    split2(v.z, h2, l2);
    split2(v.w, h3, l3);
    size_t o = (((size_t)b * TE + e0 + row) * DD + d0 + c4 * 4) >> 1;
    *(uint2*)&ehi[o] = make_uint2(h0 | (h1 << 16), h2 | (h3 << 16));
    *(uint2*)&elo[o] = make_uint2(l0 | (l1 << 16), l2 | (l3 << 16));
    TT[row][c4 * 4 + 0] = (uint16_t)h0;
    TT[row][c4 * 4 + 1] = (uint16_t)h1;
    TT[row][c4 * 4 + 2] = (uint16_t)h2;
    TT[row][c4 * 4 + 3] = (uint16_t)h3;
  }
  __syncthreads();
#pragma unroll
  for (int s = 0; s < 4; ++s) {
    int c = tid + 256 * s;
    int d = c >> 4, e4 = c & 15;
    uint32_t w0 = (uint32_t)TT[e4 * 4 + 0][d] | ((uint32_t)TT[e4 * 4 + 1][d] << 16);
    uint32_t w1 = (uint32_t)TT[e4 * 4 + 2][d] | ((uint32_t)TT[e4 * 4 + 3][d] << 16);
    *(uint2*)&eT[((size_t)b * DD + d0 + d) * TE + e0 + e4 * 4] = make_uint2(w0, w1);
  }
}

// ---------------------------------------------------------------------------
// 256x256-tile 8-phase bf16 GEMM, v4: one-quadrant-ahead register pipeline.
//   C[m][n] = sum_seg sum_k A_seg[m][k]*B_seg[n][k],  K' = NSEG*1024.
// Geometry: BK=64, 512 thr = 8 waves (2M x 4N), per-wave C = 128x64.
// LDS 128 KiB dynamic: [buf2][op2][half2][128 rows][128 B], region = 16 KiB.
// Swizzle: byte col ^= (row&7)<<4 via pre-swizzled global src + on-read XOR.
// ds_read addresses: base VGPRs + literal offsets; buffers toggle +/-65536.
// Stage src = uniform SGPR base + loop-invariant lane offset.
//
// Register pipeline: each quadrant's ds_reads issue ONE PHASE EARLY, so LDS
// banks service reads DURING MFMA windows (R4's reads-feed-own-phase made
// LDS time and MFMA time additive -> 40% MfmaUtil = LDS-serialization wall).
//   Q1 win: read bB0(cur)           ; stage B.h0(t+1)->nxt ; MFMA(a0,bA0,np0)
//   Q2 win: read a1,bB1(cur)        ; stage B.h1(t+1)->nxt ; MFMA(a0,bB0,np1)
//   Q3 win: read bA1(cur)           ;                        MFMA(a1,bB1,np1)
//   Q4 win: stage A.h0+h1(t+2)->cur ; vmcnt(4) ; BAR ;
//           read a0,bA0(nxt) [post-barrier: nxt-A guaranteed landed] ;
//           MFMA(a1,bA1,np0)
// vmcnt proof (8 loads/tile, unchanged from R3/R4): at t's vmcnt(4),
// outstanding = A(t+1)[4] + B0(t+1)[2] + B1(t+1)[2] + A(t+2)[4] = 12 ->
// drain to 4 leaves only A(t+2); tile t+1 fully landed before any of its
// reads (earliest: Q4's post-BAR a0/bA0). Staging safety: cur-A's last reads
// (a1, Q2 win) are consumed by Q3's MFMA, which every wave finished before
// any wave passes Q3's post-barrier and issues ph4's A-stage.
// ---------------------------------------------------------------------------
template <int NSEG>
__global__ __launch_bounds__(512, 2)
void k_gemm256(const uint16_t* __restrict__ a0p, const uint16_t* __restrict__ a1p,
               const uint16_t* __restrict__ a2p, const uint16_t* __restrict__ b0p,
               const uint16_t* __restrict__ b1p, const uint16_t* __restrict__ b2p,
               float* __restrict__ out) {
  extern __shared__ char lds[];
  const int tid = threadIdx.x;
  const int lane = tid & 63, wave = tid >> 6;
  const int wr = wave >> 2, wc = wave & 3;
  const int lr = lane & 15, q = lane >> 4;

  // XCD-bijective swizzle (256 blocks, 8 XCDs, 32 per chunk)
  const int id = blockIdx.x;
  const int swz = (id & 7) * 32 + (id >> 3);
  const int b = swz >> 4, mblk = (swz >> 2) & 3, nblk = swz & 3;
  const size_t bOff = (size_t)b << 20;
  const int mrow0 = mblk * 256, nrow0 = nblk * 256;
  constexpr int T = NSEG * 16;

  // ---- uniform staging bases (SGPR): seg bases with row offset folded in
  const uint16_t* aS0 = a0p + bOff + (size_t)mrow0 * 1024;
  const uint16_t* aS1 = a1p + bOff + (size_t)mrow0 * 1024;
  const uint16_t* aS2 = a2p + bOff + (size_t)mrow0 * 1024;
  const uint16_t* bS0 = b0p + bOff + (size_t)nrow0 * 1024;
  const uint16_t* bS1 = b1p + bOff + (size_t)nrow0 * 1024;
  const uint16_t* bS2 = b2p + bOff + (size_t)nrow0 * 1024;

  // ---- loop-invariant per-lane stage offset (elements)
  const int r8 = tid >> 3, c8 = tid & 7;
  const int laneOff = r8 * 1024 + ((c8 ^ (r8 & 7)) << 3);
  char* dTid = lds + tid * 16;

#define STAGE_OP(P0_, P1_, P2_, HALF_, TAU_, REGION_)                         \
  do {                                                                        \
    int sg_ = (NSEG == 3) ? ((TAU_) >> 4) : 0;                                \
    int kl_ = (TAU_) & 15;                                                    \
    const uint16_t* s_ =                                                      \
        ((NSEG == 3) ? (sg_ == 0 ? (P0_) : (sg_ == 1 ? (P1_) : (P2_)))        \
                     : (P0_)) +                                               \
        (size_t)(HALF_)*131072 + (kl_ << 6) + laneOff;                        \
    char* d_ = dTid + (REGION_)*16384;                                        \
    GLL16(s_, d_);                                                            \
    GLL16(s_ + 65536, d_ + 8192);                                             \
  } while (0)

  // ---- ds-read base pointers (buf0), literal offsets do the rest.
  const int xr = (lr & 7) << 4;
  const int colx = (q * 16) ^ xr;
  const char* aRd0 = lds + (wr << 14) + lr * 128 + colx;          // A kk0
  const char* aRd1 = lds + (wr << 14) + lr * 128 + (colx ^ 64);   // A kk1
  const char* bRdB = lds + ((2 + (wc >> 1)) << 14) + (wc & 1) * 8192 + lr * 128;
  const char* bRd0 = bRdB + colx;                                 // B kk0
  const char* bRd1 = bRdB + (colx ^ 64);                          // B kk1

  f32x4 acc[8][4] = {};
  bf16x8 a0[8], a1[8], bA0[2], bB0[2], bA1[2], bB1[2];

#define LDA_ALL(SRC_, DST_)                              \
  do {                                                   \
    _Pragma("unroll") for (int mi = 0; mi < 8; ++mi)     \
        DST_[mi] = *(const bf16x8*)((SRC_) + mi * 2048); \
  } while (0)
#define LDB2(SRC_, NB_, DST_)                               \
  do {                                                      \
    DST_[0] = *(const bf16x8*)((SRC_) + (NB_)*2048);        \
    DST_[1] = *(const bf16x8*)((SRC_) + ((NB_) + 1) * 2048);\
  } while (0)

  auto MFMAQ = [&](const bf16x8* aa, const bf16x8* bb, int npair) {
#pragma unroll
    for (int u = 0; u < 2; ++u)
#pragma unroll
      for (int mi = 0; mi < 8; ++mi)
        acc[mi][npair * 2 + u] = __builtin_amdgcn_mfma_f32_16x16x32_bf16(
            aa[mi], bb[u], acc[mi][npair * 2 + u], 0, 0, 0);
  };

  // prologue: tile0 (regions 0-3) + A(1) (regions 4,5); vmcnt(4) drains
  // tile0 exactly (A(1) stays in flight); then preload Q1's fragments.
  STAGE_OP(aS0, aS1, aS2, 0, 0, 0);
  STAGE_OP(aS0, aS1, aS2, 1, 0, 1);
  STAGE_OP(bS0, bS1, bS2, 0, 0, 2);
  STAGE_OP(bS0, bS1, bS2, 1, 0, 3);
  STAGE_OP(aS0, aS1, aS2, 0, 1, 4);
  STAGE_OP(aS0, aS1, aS2, 1, 1, 5);
  VMW4();
  BAR();
  LDA_ALL(aRd0, a0);
  LDB2(bRd0, 0, bA0);

  int dir = 65536;  // read-base toggle buf0 <-> buf1
#pragma unroll 1
  for (int t = 0; t < T; ++t) {
    const int cur = t & 1, nxt = cur ^ 1;
    const int t1 = (t + 1 < T) ? t + 1 : t + 1 - T;
    const int t2 = (t + 2 < T) ? t + 2 : t + 2 - T;
    // ---- Q1: read bB0 (for Q2) ; stage B.h0(t+1) ; MFMA(a0,bA0)
    LDB2(bRd0, 2, bB0);
    STAGE_OP(bS0, bS1, bS2, 0, t1, nxt * 4 + 2);
    BAR();
    __builtin_amdgcn_s_setprio(1);
    MFMAQ(a0, bA0, 0);
    __builtin_amdgcn_s_setprio(0);
    BAR();
    // ---- Q2: read a1,bB1 (for Q3) ; stage B.h1(t+1) ; MFMA(a0,bB0)
    LDA_ALL(aRd1, a1);
    LDB2(bRd1, 2, bB1);
    STAGE_OP(bS0, bS1, bS2, 1, t1, nxt * 4 + 3);
    BAR();
    __builtin_amdgcn_s_setprio(1);
    MFMAQ(a0, bB0, 1);
    __builtin_amdgcn_s_setprio(0);
    BAR();
    // ---- Q3: read bA1 (for Q4) ; MFMA(a1,bB1)
    LDB2(bRd1, 0, bA1);
    BAR();
    __builtin_amdgcn_s_setprio(1);
    MFMAQ(a1, bB1, 1);
    __builtin_amdgcn_s_setprio(0);
    BAR();
    // ---- Q4: stage A(t+2)->cur ; vmcnt(4) ; BAR ; read a0,bA0(nxt) ;
    //          MFMA(a1,bA1)
    STAGE_OP(aS0, aS1, aS2, 0, t2, cur * 4 + 0);
    STAGE_OP(aS0, aS1, aS2, 1, t2, cur * 4 + 1);
    VMW4();
    BAR();
    LDA_ALL(aRd0 + dir, a0);
    LDB2(bRd0 + dir, 0, bA0);
    __builtin_amdgcn_s_setprio(1);
    MFMAQ(a1, bA1, 0);
    __builtin_amdgcn_s_setprio(0);
    BAR();
    // toggle read bases to the other buffer
    aRd0 += dir;
    aRd1 += dir;
    bRd0 += dir;
    bRd1 += dir;
    dir = -dir;
  }
#undef STAGE_OP
#undef LDA_ALL
#undef LDB2

  // epilogue: C/D layout col = lane&15, row = (lane>>4)*4 + reg
  float* outp = out + (size_t)b * TD * 2048 + 1024;
  const int m0 = mrow0 + wr * 128 + q * 4;
  const int n0 = nrow0 + wc * 64 + lr;
#pragma unroll
  for (int mi = 0; mi < 8; ++mi)
#pragma unroll
    for (int ni = 0; ni < 4; ++ni)
#pragma unroll
      for (int i = 0; i < 4; ++i)
        outp[(size_t)(m0 + mi * 16 + i) * 2048 + (n0 + ni * 16)] = acc[mi][ni][i];
}

// ---------------------------------------------------------------------------
// K2 v3: softmax over e per (b,t) row; P (bf16) -> workspace.
// ---------------------------------------------------------------------------
__global__ __launch_bounds__(256)
void k2_softmax_v3(const float* __restrict__ out, uint16_t* __restrict__ P) {
  const int lane = threadIdx.x & 63;
  const int row = blockIdx.x * 4 + (threadIdx.x >> 6);
  const float* Srow = out + (size_t)row * 2048 + 1024;
  float4 v[4];
#pragma unroll
  for (int s = 0; s < 4; ++s) v[s] = *(const float4*)(Srow + lane * 4 + s * 256);
  float m = -1e30f;
#pragma unroll
  for (int s = 0; s < 4; ++s)
    m = fmaxf(m, fmaxf(fmaxf(v[s].x, v[s].y), fmaxf(v[s].z, v[s].w)));
#pragma unroll
  for (int o = 32; o > 0; o >>= 1) m = fmaxf(m, __shfl_xor(m, o));
  float e[16];
  float sum = 0.f;
#pragma unroll
  for (int s = 0; s < 4; ++s) {
    e[4 * s + 0] = __expf(v[s].x - m);
    e[4 * s + 1] = __expf(v[s].y - m);
    e[4 * s + 2] = __expf(v[s].z - m);
    e[4 * s + 3] = __expf(v[s].w - m);
    sum += e[4 * s + 0] + e[4 * s + 1] + e[4 * s + 2] + e[4 * s + 3];
  }
#pragma unroll
  for (int o = 32; o > 0; o >>= 1) sum += __shfl_xor(sum, o);
  const float inv = 1.0f / sum;
  uint32_t* Prow = (uint32_t*)(P + (size_t)row * 1024);
#pragma unroll
  for (int s = 0; s < 4; ++s) {
    uint32_t r0 = rne_bf16(e[4 * s + 0] * inv);
    uint32_t r1 = rne_bf16(e[4 * s + 1] * inv);
    uint32_t r2 = rne_bf16(e[4 * s + 2] * inv);
    uint32_t r3 = rne_bf16(e[4 * s + 3] * inv);
    *(uint2*)&Prow[lane * 2 + s * 128] =
        make_uint2(r0 | (r1 << 16), r2 | (r3 << 16));
  }
}

// ===========================================================================
// FALLBACK PATH (verified pipeline) — used if workspace/LDS attr unavailable.
// ===========================================================================
__global__ __launch_bounds__(256, 2)
void k1_scores(const float* __restrict__ dec, const float* __restrict__ enc,
               float* __restrict__ out) {
  __shared__ uint32_t AhU[2048], AlU[2048], BhU[2048], BlU[2048];
  const int tid = threadIdx.x;
  const int lane = tid & 63;
  const int wave = tid >> 6;
  const int wm = wave >> 1, wn = wave & 1;
  const int b = blockIdx.z;
  const int t0 = blockIdx.y * 128, e0 = blockIdx.x * 128;
  const float* A = dec + (size_t)b * TD * DD;
  const float* Bm = enc + (size_t)b * TE * DD;

  const int r = tid >> 3, c4 = tid & 7;
  const float* aptr = A + (size_t)(t0 + r) * DD + c4 * 4;
  const float* bptr = Bm + (size_t)(e0 + r) * DD + c4 * 4;

  const int lr = lane & 15, q = lane >> 4;
  int aoff[4], boff[4];
#pragma unroll
  for (int i = 0; i < 4; ++i) {
    aoff[i] = (wm * 64 + i * 16 + lr) * 16 + q * 4;
    boff[i] = (wn * 64 + i * 16 + lr) * 16 + q * 4;
  }

  f32x4 acc[4][4] = {};

  for (int k0 = 0; k0 < DD; k0 += 32) {
#pragma unroll
    for (int s = 0; s < 4; ++s) {
      const float4 va = *(const float4*)(aptr + (size_t)(32 * s) * DD);
      const float4 vb = *(const float4*)(bptr + (size_t)(32 * s) * DD);
      const int woff = (r + 32 * s) * 16 + c4 * 2;
      {
        uint32_t u0 = __builtin_bit_cast(uint32_t, va.x);
        uint32_t u1 = __builtin_bit_cast(uint32_t, va.y);
        uint32_t u2 = __builtin_bit_cast(uint32_t, va.z);
        uint32_t u3 = __builtin_bit_cast(uint32_t, va.w);
        uint32_t m0 = u0 & 0xFFFF0000u, m1 = u1 & 0xFFFF0000u;
        uint32_t m2 = u2 & 0xFFFF0000u, m3 = u3 & 0xFFFF0000u;
        float l0 = va.x - __builtin_bit_cast(float, m0);
        float l1 = va.y - __builtin_bit_cast(float, m1);
        float l2 = va.z - __builtin_bit_cast(float, m2);
        float l3 = va.w - __builtin_bit_cast(float, m3);
        *(uint2*)&AhU[woff] = make_uint2((m0 >> 16) | m1, (m2 >> 16) | m3);
        *(uint2*)&AlU[woff] = make_uint2(
            (__builtin_bit_cast(uint32_t, l0) >> 16) |
                (__builtin_bit_cast(uint32_t, l1) & 0xFFFF0000u),
            (__builtin_bit_cast(uint32_t, l2) >> 16) |
                (__builtin_bit_cast(uint32_t, l3) & 0xFFFF0000u));
      }
      {
        uint32_t u0 = __builtin_bit_cast(uint32_t, vb.x);
        uint32_t u1 = __builtin_bit_cast(uint32_t, vb.y);
        uint32_t u2 = __builtin_bit_cast(uint32_t, vb.z);
        uint32_t u3 = __builtin_bit_cast(uint32_t, vb.w);
        uint32_t m0 = u0 & 0xFFFF0000u, m1 = u1 & 0xFFFF0000u;
        uint32_t m2 = u2 & 0xFFFF0000u, m3 = u3 & 0xFFFF0000u;
        float l0 = vb.x - __builtin_bit_cast(float, m0);
        float l1 = vb.y - __builtin_bit_cast(float, m1);
        float l2 = vb.z - __builtin_bit_cast(float, m2);
        float l3 = vb.w - __builtin_bit_cast(float, m3);
        *(uint2*)&BhU[woff] = make_uint2((m0 >> 16) | m1, (m2 >> 16) | m3);
        *(uint2*)&BlU[woff] = make_uint2(
            (__builtin_bit_cast(uint32_t, l0) >> 16) |
                (__builtin_bit_cast(uint32_t, l1) & 0xFFFF0000u),
            (__builtin_bit_cast(uint32_t, l2) >> 16) |
                (__builtin_bit_cast(uint32_t, l3) & 0xFFFF0000u));
      }
    }
    __syncthreads();

    bf16x8 ah[4], al[4];
#pragma unroll
    for (int mi = 0; mi < 4; ++mi) {
      ah[mi] = *(const bf16x8*)&AhU[aoff[mi]];
      al[mi] = *(const bf16x8*)&AlU[aoff[mi]];
    }
#pragma unroll
    for (int ni = 0; ni < 4; ++ni) {
      bf16x8 bh = *(const bf16x8*)&BhU[boff[ni]];
      bf16x8 bl = *(const bf16x8*)&BlU[boff[ni]];
#pragma unroll
      for (int mi = 0; mi < 4; ++mi) {
        f32x4 c = acc[mi][ni];
        c = __builtin_amdgcn_mfma_f32_16x16x32_bf16(al[mi], bh, c, 0, 0, 0);
        c = __builtin_amdgcn_mfma_f32_16x16x32_bf16(ah[mi], bl, c, 0, 0, 0);
        c = __builtin_amdgcn_mfma_f32_16x16x32_bf16(ah[mi], bh, c, 0, 0, 0);
        acc[mi][ni] = c;
      }
    }
    __syncthreads();
    aptr += 32;
    bptr += 32;
  }

  float* outb = out + (size_t)b * TD * 2048 + 1024;
  const int tb = t0 + wm * 64 + q * 4;
  const int eb = e0 + wn * 64 + lr;
#pragma unroll
  for (int mi = 0; mi < 4; ++mi)
#pragma unroll
    for (int ni = 0; ni < 4; ++ni)
#pragma unroll
      for (int i = 0; i < 4; ++i)
        outb[(size_t)(tb + mi * 16 + i) * 2048 + (eb + ni * 16)] = acc[mi][ni][i];
}

__global__ __launch_bounds__(256)
void k2_softmax(float* out) {
  const int lane = threadIdx.x & 63;
  const int row = blockIdx.x * 4 + (threadIdx.x >> 6);
  float* Srow = out + (size_t)row * 2048 + 1024;
  float4 v[4];
#pragma unroll
  for (int s = 0; s < 4; ++s) v[s] = *(const float4*)(Srow + lane * 4 + s * 256);
  float m = -1e30f;
#pragma unroll
  for (int s = 0; s < 4; ++s)
    m = fmaxf(m, fmaxf(fmaxf(v[s].x, v[s].y), fmaxf(v[s].z, v[s].w)));
#pragma unroll
  for (int o = 32; o > 0; o >>= 1) m = fmaxf(m, __shfl_xor(m, o));
  float e[16];
  float sum = 0.f;
#pragma unroll
  for (int s = 0; s < 4; ++s) {
    e[4 * s + 0] = __expf(v[s].x - m);
    e[4 * s + 1] = __expf(v[s].y - m);
    e[4 * s + 2] = __expf(v[s].z - m);
    e[4 * s + 3] = __expf(v[s].w - m);
    sum += e[4 * s + 0] + e[4 * s + 1] + e[4 * s + 2] + e[4 * s + 3];
  }
#pragma unroll
  for (int o = 32; o > 0; o >>= 1) sum += __shfl_xor(sum, o);
  const float inv = 1.0f / sum;
  uint32_t* Prow = (uint32_t*)(out + (size_t)row * 2048);
#pragma unroll
  for (int s = 0; s < 4; ++s) {
    uint32_t r0 = rne_bf16(e[4 * s + 0] * inv);
    uint32_t r1 = rne_bf16(e[4 * s + 1] * inv);
    uint32_t r2 = rne_bf16(e[4 * s + 2] * inv);
    uint32_t r3 = rne_bf16(e[4 * s + 3] * inv);
    *(uint2*)&Prow[lane * 2 + s * 128] =
        make_uint2(r0 | (r1 << 16), r2 | (r3 << 16));
  }
}

__global__ __launch_bounds__(256, 2)
void k3_av(const float* __restrict__ enc, float* __restrict__ out) {
  __shared__ uint32_t AU[2048];
  __shared__ uint32_t BtU[128 * 20];
  const int tid = threadIdx.x;
  const int lane = tid & 63, wave = tid >> 6;
  const int wm = wave >> 1, wn = wave & 1;
  const int b = blockIdx.z;
  const int t0 = blockIdx.y * 128, d0 = blockIdx.x * 128;
  const float* V = enc + (size_t)b * TE * DD;
  const uint16_t* Pb = (const uint16_t*)(out + (size_t)b * TD * 2048);
  const int lr = lane & 15, q = lane >> 4;
  int aoff[4], boff[4];
#pragma unroll
  for (int i = 0; i < 4; ++i) {
    aoff[i] = (wm * 64 + i * 16 + lr) * 16 + q * 4;
    boff[i] = (wn * 64 + i * 16 + lr) * 20 + q * 4;
  }
  const int dB = tid & 127;
  f32x4 acc[4][4] = {};

  for (int e0k = 0; e0k < TE; e0k += 32) {
#pragma unroll
    for (int s = 0; s < 2; ++s) {
      int c = tid + 256 * s;
      int rc = c >> 2, cc = c & 3;
      uint4 va = *(const uint4*)(Pb + (size_t)(t0 + rc) * 4096 + e0k + cc * 8);
      *(uint4*)&AU[c * 4] = va;
    }
#pragma unroll
    for (int s = 0; s < 4; ++s) {
      int eg = (tid >> 7) + 2 * s;
      const float* src = V + (size_t)(e0k + eg * 4) * DD + d0 + dB;
      float x0 = src[0], x1 = src[DD], x2 = src[2 * DD], x3 = src[3 * DD];
      uint32_t r0 = rne_bf16(x0), r1 = rne_bf16(x1);
      uint32_t r2 = rne_bf16(x2), r3 = rne_bf16(x3);
      *(uint2*)&BtU[dB * 20 + eg * 2] =
          make_uint2(r0 | (r1 << 16), r2 | (r3 << 16));
    }
    __syncthreads();

    bf16x8 af[4];
#pragma unroll
    for (int mi = 0; mi < 4; ++mi) af[mi] = *(const bf16x8*)&AU[aoff[mi]];
#pragma unroll
    for (int ni = 0; ni < 4; ++ni) {
      bf16x8 bfr = *(const bf16x8*)&BtU[boff[ni]];
#pragma unroll
      for (int mi = 0; mi < 4; ++mi)
        acc[mi][ni] =
            __builtin_amdgcn_mfma_f32_16x16x32_bf16(af[mi], bfr, acc[mi][ni], 0, 0, 0);
    }
    __syncthreads();
  }

  float* outb = out + (size_t)b * TD * 2048 + 1024;
  const int tb = t0 + wm * 64 + q * 4;
  const int db = d0 + wn * 64 + lr;
#pragma unroll
  for (int mi = 0; mi < 4; ++mi)
#pragma unroll
    for (int ni = 0; ni < 4; ++ni)
#pragma unroll
      for (int i = 0; i < 4; ++i)
        outb[(size_t)(tb + mi * 16 + i) * 2048 + (db + ni * 16)] = acc[mi][ni][i];
}

__global__ __launch_bounds__(256)
void k4_copydec(const float4* __restrict__ dec4, float4* __restrict__ out4) {
  size_t g = (size_t)blockIdx.x * 512 + threadIdx.x;
#pragma unroll
  for (int s = 0; s < 2; ++s, g += 256) {
    size_t row = g >> 8, col = g & 255;
    out4[row * 512 + col] = dec4[g];
  }
}

extern "C" void kernel_launch(void* const* d_in, const int* in_sizes, int n_in,
                              void* d_out, int out_size, void* d_ws, size_t ws_size,
                              hipStream_t stream) {
  // setup_inputs order: [0]=encoder_outputs, [1]=decoder_outputs (fp32)
  const float* enc = (const float*)d_in[0];
  const float* dec = (const float*)d_in[1];
  float* out = (float*)d_out;

  const size_t M32 = 32ull << 20;  // 32 MiB per bf16 tensor
  bool fast = (d_ws != nullptr) && (ws_size >= 5 * M32);
  if (fast) {
    hipError_t e1 = hipFuncSetAttribute(
        (const void*)k_gemm256<3>, hipFuncAttributeMaxDynamicSharedMemorySize,
        131072);
    hipError_t e2 = hipFuncSetAttribute(
        (const void*)k_gemm256<1>, hipFuncAttributeMaxDynamicSharedMemorySize,
        131072);
    if (e1 != hipSuccess || e2 != hipSuccess) fast = false;
  }

  if (fast) {
    char* ws = (char*)d_ws;
    uint16_t* dhi = (uint16_t*)(ws);
    uint16_t* dlo = (uint16_t*)(ws + M32);
    uint16_t* ehi = (uint16_t*)(ws + 2 * M32);
    uint16_t* elo = (uint16_t*)(ws + 3 * M32);
    uint16_t* eT = (uint16_t*)(ws + 4 * M32);
    uint16_t* P = dhi;  // dec_hi region dead after K1; reuse for P

    hipLaunchKernelGGL(p0a_split_dec, dim3(2048), dim3(256), 0, stream,
                       (const float4*)dec, (uint32_t*)dhi, (uint32_t*)dlo,
                       (float4*)out);
    hipLaunchKernelGGL(p0b_split_enc, dim3(256, 1, 16), dim3(256), 0, stream,
                       enc, (uint32_t*)ehi, (uint32_t*)elo, eT);
    // S = Ah*Bh + Ah*Bl + Al*Bh  (K' = 3072 via segment pointers)
    hipLaunchKernelGGL(k_gemm256<3>, dim3(256), dim3(512), 131072, stream,
                       dhi, dhi, dlo, ehi, elo, ehi, out);
    hipLaunchKernelGGL(k2_softmax_v3, dim3(4096), dim3(256), 0, stream, out, P);
    // ctx = P @ encT  (K' = 1024)
    hipLaunchKernelGGL(k_gemm256<1>, dim3(256), dim3(512), 131072, stream,
                       P, P, P, eT, eT, eT, out);
  } else {
    hipLaunchKernelGGL(k1_scores, dim3(8, 8, 16), dim3(256), 0, stream, dec, enc, out);
    hipLaunchKernelGGL(k2_softmax, dim3(4096), dim3(256), 0, stream, out);
    hipLaunchKernelGGL(k3_av, dim3(8, 8, 16), dim3(256), 0, stream, enc, out);
    hipLaunchKernelGGL(k4_copydec, dim3(8192), dim3(256), 0, stream,
                       (const float4*)dec, (float4*)out);
  }
}